// Round 5
// baseline (1101.006 us; speedup 1.0000x reference)
//
#include <hip/hip_runtime.h>
#include <math.h>

#define B_    16
#define NP_   64
#define J_    17
#define C_    480
#define H_    128
#define W_    128
#define L_    4
#define HW_   (H_ * W_)
#define NSAMP (B_ * NP_)      // 1024
#define MROWS (NSAMP * J_)    // 17408
#define EPS_  1e-5f
#define NMAT  (1 + 2 * L_)    // 9 graph-conv weight matrices
#define NPAD  512             // weight N padded to 512 rows (zero-filled) for maskless staging

typedef __attribute__((ext_vector_type(8))) short bf16x8;
typedef __attribute__((ext_vector_type(4))) float f32x4;

__device__ __forceinline__ unsigned short f2bf(float f) {
    unsigned int u = __float_as_uint(f);
    unsigned int r = (u + 0x7fffu + ((u >> 16) & 1u)) >> 16;
    return (unsigned short)r;
}
__device__ __forceinline__ float bf2f(unsigned short h) {
    return __uint_as_float(((unsigned int)h) << 16);
}

// async global->LDS, 16B per lane; LDS dest = base + lane*16 (wave-uniform base)
#define GLD16(gsrc, ldst)                                                                 \
    __builtin_amdgcn_global_load_lds((const __attribute__((address_space(1))) void*)(gsrc), \
                                     (__attribute__((address_space(3))) void*)(ldst), 16, 0, 0)

// ---------------- fused bilinear sampling + head adjacency mix -> bf16 A ----------------
__global__ __launch_bounds__(256) void k_sample_mix(const float* __restrict__ feat,
                                                    const float* __restrict__ coords,
                                                    const float* __restrict__ adj,
                                                    short* __restrict__ Ah) {
    __shared__ float sX[J_][C_];       // sampled joint features
    __shared__ float sadj[J_ * J_];
    __shared__ float sw[J_][4];        // bilinear weights
    __shared__ int   si[J_];           // i00 per joint
    int n = blockIdx.x;                // 0..NSAMP-1
    int b = n / NP_;
    for (int t = threadIdx.x; t < J_ * J_; t += 256) sadj[t] = adj[t];
    if (threadIdx.x < J_) {
        int j = threadIdx.x;
        int p = n * J_ + j;
        float x = coords[p * 2 + 0];
        float y = coords[p * 2 + 1];
        float x0f = fminf(fmaxf(floorf(x), 0.f), (float)(W_ - 2));
        float y0f = fminf(fmaxf(floorf(y), 0.f), (float)(H_ - 2));
        float wx = x - x0f, wy = y - y0f;
        sw[j][0] = (1.f - wx) * (1.f - wy);
        sw[j][1] = wx * (1.f - wy);
        sw[j][2] = (1.f - wx) * wy;
        sw[j][3] = wx * wy;
        si[j] = (int)y0f * W_ + (int)x0f;
    }
    __syncthreads();
    const float* base = feat + (size_t)b * C_ * HW_;
    for (int idx = threadIdx.x; idx < J_ * C_; idx += 256) {
        int j = idx / C_, c = idx % C_;
        const float* pc = base + (size_t)c * HW_ + si[j];
        sX[j][c] = pc[0] * sw[j][0] + pc[1] * sw[j][1] + pc[W_] * sw[j][2] + pc[W_ + 1] * sw[j][3];
    }
    __syncthreads();
    size_t obase = (size_t)n * J_ * C_;
    for (int c = threadIdx.x; c < C_; c += 256) {
        float xv[J_];
        #pragma unroll
        for (int k = 0; k < J_; k++) xv[k] = sX[k][c];
        #pragma unroll
        for (int j = 0; j < J_; j++) {
            float s = 0.f;
            #pragma unroll
            for (int k = 0; k < J_; k++) s += sadj[j * J_ + k] * xv[k];
            Ah[obase + (size_t)j * C_ + c] = (short)f2bf(s);
        }
    }
}

// ---------------- center gather ----------------
__global__ __launch_bounds__(256) void k_center(const float* __restrict__ feat,
                                                const int* __restrict__ cidx,
                                                float* __restrict__ Cf) {
    int bn = blockIdx.x;
    int b  = bn / NP_;
    int idx = cidx[bn];
    const float* base = feat + (size_t)b * C_ * HW_ + idx;
    for (int c = threadIdx.x; c < C_; c += 256)
        Cf[(size_t)bn * C_ + c] = base[(size_t)c * HW_];
}

// ---------------- weight split into padded [NPAD][K] hi/lo bf16 ----------------
// conv: W[k][n] -> Wt[m][n][k] (transpose); pred: Wp1[n][k] -> direct; rows n>=C_ zeroed.
__global__ __launch_bounds__(256) void k_wsplit(const float* __restrict__ Wh,
                                                const float* __restrict__ Wres,
                                                const float* __restrict__ Wp1,
                                                short* __restrict__ WtH,
                                                short* __restrict__ WtL,
                                                short* __restrict__ WpH,
                                                short* __restrict__ WpL) {
    int gid = blockIdx.x * 256 + threadIdx.x;
    const int t1 = NMAT * NPAD * C_;
    const int t2 = NPAD * 3 * C_;
    if (gid < t1) {
        int m   = gid / (NPAD * C_);
        int rem = gid % (NPAD * C_);
        int n = rem / C_;
        int k = rem % C_;
        float v = 0.f;
        if (n < C_) {
            const float* src = (m == 0) ? Wh : (Wres + (size_t)(m - 1) * C_ * C_);
            v = src[(size_t)k * C_ + n];
        }
        unsigned short h = f2bf(v);
        WtH[gid] = (short)h;
        WtL[gid] = (short)f2bf(v - bf2f(h));
    } else if (gid < t1 + t2) {
        int g2 = gid - t1;
        int n = g2 / (3 * C_);
        int k = g2 % (3 * C_);
        float v = (n < C_) ? Wp1[(size_t)n * 3 * C_ + k] : 0.f;
        unsigned short h = f2bf(v);
        WpH[g2] = (short)h;
        WpL[g2] = (short)f2bf(v - bf2f(h));
    }
}

// ---------------- adjacency mix -> bf16 A [MROWS][C] ----------------
__global__ __launch_bounds__(256) void k_mix_bf16(const float* __restrict__ Xin,
                                                  const float* __restrict__ adj,
                                                  short* __restrict__ Ah) {
    __shared__ float sadj[J_ * J_];
    for (int t = threadIdx.x; t < J_ * J_; t += 256) sadj[t] = adj[t];
    __syncthreads();
    int n = blockIdx.x;
    const float* xb = Xin + (size_t)n * J_ * C_;
    size_t obase = (size_t)n * J_ * C_;
    for (int c = threadIdx.x; c < C_; c += 256) {
        float xv[J_];
        #pragma unroll
        for (int k = 0; k < J_; k++) xv[k] = xb[(size_t)k * C_ + c];
        #pragma unroll
        for (int j = 0; j < J_; j++) {
            float s = 0.f;
            #pragma unroll
            for (int k = 0; k < J_; k++) s += sadj[j * J_ + k] * xv[k];
            Ah[obase + (size_t)j * C_ + c] = (short)f2bf(s);
        }
    }
}

// ---------------- 2-term split MFMA GEMM, global_load_lds staging ----------------
// out[m,n] = relu(bn(sum_k A[m,k]B[k,n] + bias[n])) (+ res)
// A bf16 [M][K]; B split Bh/Bl bf16 [NPAD][K] (transposed, rows>=N zero).
// LDS swizzle byte p = (r*64 + cq*16) ^ ((r&7)<<4); staged linearly by global_load_lds
// with inverse-swizzled per-lane SOURCE addresses (rule: linear dest + inv-swz src + swz read).
template <bool ADD>
__global__ __launch_bounds__(256) void k_gemm_mfma(const short* __restrict__ A,
                                                   const short* __restrict__ Bh,
                                                   const short* __restrict__ Bl,
                                                   const float* __restrict__ bias,
                                                   const float* __restrict__ bn4,
                                                   const float* res,   // may alias out
                                                   float* out,
                                                   int M, int N, int K) {
    __shared__ short lds[3 * 4096];   // sA | sBh | sBl, each 8 KB ([128 rows][32 k] swizzled)
    short* sA  = lds;
    short* sBh = lds + 4096;
    short* sBl = lds + 8192;

    const int tid  = threadIdx.x;
    const int lane = tid & 63;
    const int wid  = tid >> 6;
    const int wm0  = (wid >> 1) * 64;
    const int wn0  = (wid & 1) * 64;
    const int row0 = blockIdx.y * 128;
    const int col0 = blockIdx.x * 128;

    f32x4 acc[4][4];
    #pragma unroll
    for (int i = 0; i < 4; i++)
        #pragma unroll
        for (int j = 0; j < 4; j++) acc[i][j] = (f32x4){0.f, 0.f, 0.f, 0.f};

    const int kq = lane >> 4;
    const int fr = lane & 15;

    // --- per-lane inverse-swizzle source mapping for the 2 staging calls this wave makes ---
    // call t covers LDS bytes [(2*wid+t)*1024, +1024); this lane writes p = that + lane*16.
    int r_[2], cq_[2];
    #pragma unroll
    for (int t = 0; t < 2; ++t) {
        int p = (2 * wid + t) * 1024 + lane * 16;
        int v = p >> 6;
        int r = v ^ ((v >> 2) & 1);
        r_[t]  = r;
        cq_[t] = ((p >> 4) & 3) ^ (r & 3);
    }
    const short* pA0  = A  + (size_t)(row0 + r_[0]) * K + cq_[0] * 8;
    const short* pA1  = A  + (size_t)(row0 + r_[1]) * K + cq_[1] * 8;
    const short* pBh0 = Bh + (size_t)(col0 + r_[0]) * K + cq_[0] * 8;
    const short* pBh1 = Bh + (size_t)(col0 + r_[1]) * K + cq_[1] * 8;
    const short* pBl0 = Bl + (size_t)(col0 + r_[0]) * K + cq_[0] * 8;
    const short* pBl1 = Bl + (size_t)(col0 + r_[1]) * K + cq_[1] * 8;
    char* ldsA0  = (char*)sA  + (2 * wid + 0) * 1024;
    char* ldsA1  = (char*)sA  + (2 * wid + 1) * 1024;
    char* ldsBh0 = (char*)sBh + (2 * wid + 0) * 1024;
    char* ldsBh1 = (char*)sBh + (2 * wid + 1) * 1024;
    char* ldsBl0 = (char*)sBl + (2 * wid + 0) * 1024;
    char* ldsBl1 = (char*)sBl + (2 * wid + 1) * 1024;

    for (int kk = 0; kk < K; kk += 32) {
        GLD16(pA0 + kk, ldsA0);
        GLD16(pA1 + kk, ldsA1);
        GLD16(pBh0 + kk, ldsBh0);
        GLD16(pBh1 + kk, ldsBh1);
        GLD16(pBl0 + kk, ldsBl0);
        GLD16(pBl1 + kk, ldsBl1);
        __syncthreads();    // drains vmcnt(0): LDS tiles complete

        bf16x8 fa[4], fbh[4], fbl[4];
        #pragma unroll
        for (int mf = 0; mf < 4; ++mf) {
            int r  = wm0 + mf * 16 + fr;
            int so = ((r * 64 + kq * 16) ^ ((r & 7) << 4)) >> 1;
            fa[mf] = *reinterpret_cast<const bf16x8*>(sA + so);
        }
        #pragma unroll
        for (int nf = 0; nf < 4; ++nf) {
            int r  = wn0 + nf * 16 + fr;
            int so = ((r * 64 + kq * 16) ^ ((r & 7) << 4)) >> 1;
            fbh[nf] = *reinterpret_cast<const bf16x8*>(sBh + so);
            fbl[nf] = *reinterpret_cast<const bf16x8*>(sBl + so);
        }
        #pragma unroll
        for (int mf = 0; mf < 4; ++mf)
            #pragma unroll
            for (int nf = 0; nf < 4; ++nf) {
                acc[mf][nf] = __builtin_amdgcn_mfma_f32_16x16x32_bf16(fa[mf], fbh[nf], acc[mf][nf], 0, 0, 0);
                acc[mf][nf] = __builtin_amdgcn_mfma_f32_16x16x32_bf16(fa[mf], fbl[nf], acc[mf][nf], 0, 0, 0);
            }
        __syncthreads();    // all reads done before next-step staging overwrites
    }

    // ---- epilogue: C/D layout col=lane&15, row=(lane>>4)*4+reg ----
    const int rq = lane >> 4;
    #pragma unroll
    for (int nf = 0; nf < 4; ++nf) {
        int col = col0 + wn0 + nf * 16 + fr;
        if (col >= N) continue;
        float bia = bias[col];
        float g   = bn4[col];
        float be  = bn4[N + col];
        float mu  = bn4[2 * N + col];
        float va  = bn4[3 * N + col];
        float sc  = rsqrtf(va + EPS_) * g;
        #pragma unroll
        for (int mf = 0; mf < 4; ++mf) {
            #pragma unroll
            for (int r = 0; r < 4; ++r) {
                int row = row0 + wm0 + mf * 16 + rq * 4 + r;
                float v = acc[mf][nf][r] + bia;
                v = (v - mu) * sc + be;
                v = fmaxf(v, 0.f);
                if (ADD) v += res[(size_t)row * N + col];
                out[(size_t)row * N + col] = v;
            }
        }
    }
}

// ---------------- pooling + concat -> bf16 feats [NSAMP][3C] ----------------
__global__ __launch_bounds__(256) void k_pool(const float* __restrict__ Hb,
                                              const float* __restrict__ Cen,
                                              short* __restrict__ feats) {
    int n = blockIdx.x;
    for (int c = threadIdx.x; c < C_; c += 256) {
        float s = 0.f, m = -INFINITY;
        #pragma unroll
        for (int j = 0; j < J_; j++) {
            float v = Hb[((size_t)n * J_ + j) * C_ + c];
            s += v;
            m = fmaxf(m, v);
        }
        feats[(size_t)n * 3 * C_ + c]          = (short)f2bf(s * (1.f / (float)J_));
        feats[(size_t)n * 3 * C_ + C_ + c]     = (short)f2bf(m);
        feats[(size_t)n * 3 * C_ + 2 * C_ + c] = (short)f2bf(Cen[(size_t)n * C_ + c]);
    }
}

// ---------------- final projection ----------------
__global__ __launch_bounds__(256) void k_final(const float* __restrict__ P,
                                               const float* __restrict__ W2,
                                               const float* __restrict__ b2,
                                               float* __restrict__ out) {
    int g = blockIdx.x * 256 + threadIdx.x;
    if (g >= NSAMP * 2 * J_) return;
    int m = g / (2 * J_);
    int o = g % (2 * J_);
    const float* pr = P + (size_t)m * C_;
    const float* wr = W2 + (size_t)o * C_;
    float s = 0.f;
    for (int k = 0; k < C_; k += 4) {
        s = fmaf(pr[k + 0], wr[k + 0], s);
        s = fmaf(pr[k + 1], wr[k + 1], s);
        s = fmaf(pr[k + 2], wr[k + 2], s);
        s = fmaf(pr[k + 3], wr[k + 3], s);
    }
    out[g] = s + b2[o];
}

extern "C" void kernel_launch(void* const* d_in, const int* in_sizes, int n_in,
                              void* d_out, int out_size, void* d_ws, size_t ws_size,
                              hipStream_t stream) {
    const float* features = (const float*)d_in[0];
    const float* coords   = (const float*)d_in[1];
    const int*   center   = (const int*)d_in[2];
    const float* adj      = (const float*)d_in[3];
    const float* Wh       = (const float*)d_in[4];
    const float* bh       = (const float*)d_in[5];
    const float* bn_head  = (const float*)d_in[6];
    const float* Wres     = (const float*)d_in[7];
    const float* bres     = (const float*)d_in[8];
    const float* bn_res   = (const float*)d_in[9];
    const float* Wp1      = (const float*)d_in[10];
    const float* bp1      = (const float*)d_in[11];
    const float* bn_pred  = (const float*)d_in[12];
    const float* Wp2      = (const float*)d_in[13];
    const float* bp2      = (const float*)d_in[14];
    float* out = (float*)d_out;

    // ---- workspace layout ----
    char* ws = (char*)d_ws;
    float* bufX  = (float*)ws;   ws += (size_t)MROWS * C_ * 4;        // f32 [MROWS,C]
    float* bufH  = (float*)ws;   ws += (size_t)MROWS * C_ * 4;
    short* AhB   = (short*)ws;   ws += (size_t)MROWS * C_ * 2;        // bf16 A
    float* bufC  = (float*)ws;   ws += (size_t)NSAMP * C_ * 4;
    short* featsB= (short*)ws;   ws += (size_t)NSAMP * 3 * C_ * 2;    // bf16 feats
    float* bufP  = (float*)ws;   ws += (size_t)NSAMP * C_ * 4;
    short* WtH   = (short*)ws;   ws += (size_t)NMAT * NPAD * C_ * 2;  // padded [512][480]
    short* WtL   = (short*)ws;   ws += (size_t)NMAT * NPAD * C_ * 2;
    short* WpH   = (short*)ws;   ws += (size_t)NPAD * 3 * C_ * 2;     // padded [512][1440]
    short* WpL   = (short*)ws;   ws += (size_t)NPAD * 3 * C_ * 2;

    dim3 gg(4, MROWS / 128);
    dim3 gp(4, NSAMP / 128);

    int wtot = NMAT * NPAD * C_ + NPAD * 3 * C_;
    k_wsplit<<<(wtot + 255) / 256, 256, 0, stream>>>(Wh, Wres, Wp1, WtH, WtL, WpH, WpL);
    k_center<<<NSAMP, 256, 0, stream>>>(features, center, bufC);

    // head block: fused sample+mix -> bf16 A, then GEMM
    k_sample_mix<<<NSAMP, 256, 0, stream>>>(features, coords, adj, AhB);
    k_gemm_mfma<false><<<gg, 256, 0, stream>>>(AhB, WtH, WtL, bh, bn_head,
                                               nullptr, bufH, MROWS, C_, C_);

    for (int i = 0; i < L_; i++) {
        int m1 = 1 + 2 * i, m2 = 2 + 2 * i;
        k_mix_bf16<<<NSAMP, 256, 0, stream>>>(bufH, adj, AhB);
        k_gemm_mfma<false><<<gg, 256, 0, stream>>>(
            AhB, WtH + (size_t)m1 * NPAD * C_, WtL + (size_t)m1 * NPAD * C_,
            bres + (size_t)(2 * i) * C_, bn_res + (size_t)(2 * i) * 4 * C_,
            nullptr, bufX, MROWS, C_, C_);
        k_mix_bf16<<<NSAMP, 256, 0, stream>>>(bufX, adj, AhB);
        k_gemm_mfma<true><<<gg, 256, 0, stream>>>(
            AhB, WtH + (size_t)m2 * NPAD * C_, WtL + (size_t)m2 * NPAD * C_,
            bres + (size_t)(2 * i + 1) * C_, bn_res + (size_t)(2 * i + 1) * 4 * C_,
            bufH, bufH, MROWS, C_, C_);
    }

    k_pool<<<NSAMP, 256, 0, stream>>>(bufH, bufC, featsB);

    // pred: relu(bn(feats @ Wp1^T + bp1)); M=1024, N=480, K=1440
    k_gemm_mfma<false><<<gp, 256, 0, stream>>>(featsB, WpH, WpL, bp1, bn_pred,
                                               nullptr, bufP, NSAMP, C_, 3 * C_);

    k_final<<<(NSAMP * 2 * J_ + 255) / 256, 256, 0, stream>>>(bufP, Wp2, bp2, out);
}

// Round 6
// 980.880 us; speedup vs baseline: 1.1225x; 1.1225x over previous
//
#include <hip/hip_runtime.h>
#include <math.h>

#define B_    16
#define NP_   64
#define J_    17
#define C_    480
#define H_    128
#define W_    128
#define L_    4
#define HW_   (H_ * W_)
#define NSAMP (B_ * NP_)      // 1024
#define MROWS (NSAMP * J_)    // 17408
#define EPS_  1e-5f
#define NMAT  (1 + 2 * L_)    // 9 graph-conv weight matrices
#define NPAD  512             // weight N padded to 512 rows (zero-filled) for maskless staging
#define TC    96              // transpose tile: channels
#define TS    64              // transpose tile: spatial

typedef __attribute__((ext_vector_type(8))) short bf16x8;
typedef __attribute__((ext_vector_type(4))) float f32x4;

__device__ __forceinline__ unsigned short f2bf(float f) {
    unsigned int u = __float_as_uint(f);
    unsigned int r = (u + 0x7fffu + ((u >> 16) & 1u)) >> 16;
    return (unsigned short)r;
}
__device__ __forceinline__ float bf2f(unsigned short h) {
    return __uint_as_float(((unsigned int)h) << 16);
}

// async global->LDS, 16B per lane; LDS dest = base + lane*16 (wave-uniform base)
#define GLD16(gsrc, ldst)                                                                 \
    __builtin_amdgcn_global_load_lds((const __attribute__((address_space(1))) void*)(gsrc), \
                                     (__attribute__((address_space(3))) void*)(ldst), 16, 0, 0)

// ---------------- NCHW f32 -> NHWC bf16 transpose (tiled, both sides coalesced) ----------------
__global__ __launch_bounds__(256) void k_nhwc(const float* __restrict__ feat,
                                              short* __restrict__ nhwc) {
    __shared__ float t[TC][TS + 1];
    int b  = blockIdx.z;
    int c0 = blockIdx.y * TC;
    int s0 = blockIdx.x * TS;
    const float* src = feat + ((size_t)b * C_ + c0) * HW_ + s0;
    int cy = threadIdx.x >> 6;          // 0..3
    int sx = threadIdx.x & 63;
    #pragma unroll
    for (int i = 0; i < TC / 4; ++i) {  // 24 rows per thread-slice
        int c = cy + i * 4;
        t[c][sx] = src[(size_t)c * HW_ + sx];
    }
    __syncthreads();
    int sy = threadIdx.x >> 2;                 // 0..63
    int cx = (threadIdx.x & 3) * (TC / 4);     // 0,24,48,72
    short* dst = nhwc + ((size_t)b * HW_ + s0 + sy) * C_ + c0 + cx;
    alignas(16) unsigned short tmp[TC / 4];
    #pragma unroll
    for (int i = 0; i < TC / 4; ++i) tmp[i] = f2bf(t[cx + i][sy]);
    #pragma unroll
    for (int i = 0; i < 3; ++i)
        *reinterpret_cast<uint4*>(dst + i * 8) = *reinterpret_cast<const uint4*>(tmp + i * 8);
}

// ---------------- fused bilinear gather (from NHWC bf16) + head adjacency mix -> bf16 A ----------------
__global__ __launch_bounds__(256) void k_gather_mix(const short* __restrict__ nhwc,
                                                    const float* __restrict__ coords,
                                                    const float* __restrict__ adj,
                                                    short* __restrict__ Ah) {
    __shared__ float sX[J_][C_];
    __shared__ float sadj[J_ * J_];
    __shared__ float sw[J_][4];
    __shared__ int   si[J_];
    int n = blockIdx.x;                // 0..NSAMP-1
    int b = n / NP_;
    for (int t = threadIdx.x; t < J_ * J_; t += 256) sadj[t] = adj[t];
    if (threadIdx.x < J_) {
        int j = threadIdx.x;
        int p = n * J_ + j;
        float x = coords[p * 2 + 0];
        float y = coords[p * 2 + 1];
        float x0f = fminf(fmaxf(floorf(x), 0.f), (float)(W_ - 2));
        float y0f = fminf(fmaxf(floorf(y), 0.f), (float)(H_ - 2));
        float wx = x - x0f, wy = y - y0f;
        sw[j][0] = (1.f - wx) * (1.f - wy);
        sw[j][1] = wx * (1.f - wy);
        sw[j][2] = (1.f - wx) * wy;
        sw[j][3] = wx * wy;
        si[j] = (int)y0f * W_ + (int)x0f;
    }
    __syncthreads();
    const short* base = nhwc + (size_t)b * HW_ * C_;
    // 8 channels per thread per iter: J*(C/8) = 17*60 = 1020 chunks
    for (int idx = threadIdx.x; idx < J_ * (C_ / 8); idx += 256) {
        int j  = idx / (C_ / 8);
        int c8 = (idx - j * (C_ / 8)) * 8;
        const short* p00 = base + (size_t)si[j] * C_ + c8;
        bf16x8 v00 = *reinterpret_cast<const bf16x8*>(p00);
        bf16x8 v01 = *reinterpret_cast<const bf16x8*>(p00 + C_);
        bf16x8 v10 = *reinterpret_cast<const bf16x8*>(p00 + W_ * C_);
        bf16x8 v11 = *reinterpret_cast<const bf16x8*>(p00 + W_ * C_ + C_);
        float w0 = sw[j][0], w1 = sw[j][1], w2 = sw[j][2], w3 = sw[j][3];
        #pragma unroll
        for (int e = 0; e < 8; ++e) {
            sX[j][c8 + e] = bf2f((unsigned short)v00[e]) * w0 +
                            bf2f((unsigned short)v01[e]) * w1 +
                            bf2f((unsigned short)v10[e]) * w2 +
                            bf2f((unsigned short)v11[e]) * w3;
        }
    }
    __syncthreads();
    size_t obase = (size_t)n * J_ * C_;
    for (int c = threadIdx.x; c < C_; c += 256) {
        float xv[J_];
        #pragma unroll
        for (int k = 0; k < J_; k++) xv[k] = sX[k][c];
        #pragma unroll
        for (int j = 0; j < J_; j++) {
            float s = 0.f;
            #pragma unroll
            for (int k = 0; k < J_; k++) s += sadj[j * J_ + k] * xv[k];
            Ah[obase + (size_t)j * C_ + c] = (short)f2bf(s);
        }
    }
}

// ---------------- center gather from NHWC ----------------
__global__ __launch_bounds__(256) void k_center(const short* __restrict__ nhwc,
                                                const int* __restrict__ cidx,
                                                float* __restrict__ Cf) {
    int bn = blockIdx.x;
    int b  = bn / NP_;
    int s  = cidx[bn];
    const short* src = nhwc + ((size_t)b * HW_ + s) * C_;
    for (int c = threadIdx.x; c < C_; c += 256)
        Cf[(size_t)bn * C_ + c] = bf2f((unsigned short)src[c]);
}

// ---------------- weight split into padded [NPAD][K] hi/lo bf16 ----------------
__global__ __launch_bounds__(256) void k_wsplit(const float* __restrict__ Wh,
                                                const float* __restrict__ Wres,
                                                const float* __restrict__ Wp1,
                                                short* __restrict__ WtH,
                                                short* __restrict__ WtL,
                                                short* __restrict__ WpH,
                                                short* __restrict__ WpL) {
    int gid = blockIdx.x * 256 + threadIdx.x;
    const int t1 = NMAT * NPAD * C_;
    const int t2 = NPAD * 3 * C_;
    if (gid < t1) {
        int m   = gid / (NPAD * C_);
        int rem = gid % (NPAD * C_);
        int n = rem / C_;
        int k = rem % C_;
        float v = 0.f;
        if (n < C_) {
            const float* src = (m == 0) ? Wh : (Wres + (size_t)(m - 1) * C_ * C_);
            v = src[(size_t)k * C_ + n];
        }
        unsigned short h = f2bf(v);
        WtH[gid] = (short)h;
        WtL[gid] = (short)f2bf(v - bf2f(h));
    } else if (gid < t1 + t2) {
        int g2 = gid - t1;
        int n = g2 / (3 * C_);
        int k = g2 % (3 * C_);
        float v = (n < C_) ? Wp1[(size_t)n * 3 * C_ + k] : 0.f;
        unsigned short h = f2bf(v);
        WpH[g2] = (short)h;
        WpL[g2] = (short)f2bf(v - bf2f(h));
    }
}

// ---------------- adjacency mix -> bf16 A [MROWS][C] ----------------
__global__ __launch_bounds__(256) void k_mix_bf16(const float* __restrict__ Xin,
                                                  const float* __restrict__ adj,
                                                  short* __restrict__ Ah) {
    __shared__ float sadj[J_ * J_];
    for (int t = threadIdx.x; t < J_ * J_; t += 256) sadj[t] = adj[t];
    __syncthreads();
    int n = blockIdx.x;
    const float* xb = Xin + (size_t)n * J_ * C_;
    size_t obase = (size_t)n * J_ * C_;
    for (int c = threadIdx.x; c < C_; c += 256) {
        float xv[J_];
        #pragma unroll
        for (int k = 0; k < J_; k++) xv[k] = xb[(size_t)k * C_ + c];
        #pragma unroll
        for (int j = 0; j < J_; j++) {
            float s = 0.f;
            #pragma unroll
            for (int k = 0; k < J_; k++) s += sadj[j * J_ + k] * xv[k];
            Ah[obase + (size_t)j * C_ + c] = (short)f2bf(s);
        }
    }
}

// ---------------- 2-term split MFMA GEMM, global_load_lds staging ----------------
// LDS swizzle byte p = (r*64 + cq*16) ^ ((r&7)<<4); staged linearly by global_load_lds
// with inverse-swizzled per-lane SOURCE addresses (linear dest + inv-swz src + swz read).
template <bool ADD>
__global__ __launch_bounds__(256) void k_gemm_mfma(const short* __restrict__ A,
                                                   const short* __restrict__ Bh,
                                                   const short* __restrict__ Bl,
                                                   const float* __restrict__ bias,
                                                   const float* __restrict__ bn4,
                                                   const float* res,   // may alias out
                                                   float* out,
                                                   int M, int N, int K) {
    __shared__ short lds[3 * 4096];   // sA | sBh | sBl, each 8 KB ([128 rows][32 k] swizzled)
    short* sA  = lds;
    short* sBh = lds + 4096;
    short* sBl = lds + 8192;

    const int tid  = threadIdx.x;
    const int lane = tid & 63;
    const int wid  = tid >> 6;
    const int wm0  = (wid >> 1) * 64;
    const int wn0  = (wid & 1) * 64;
    const int row0 = blockIdx.y * 128;
    const int col0 = blockIdx.x * 128;

    f32x4 acc[4][4];
    #pragma unroll
    for (int i = 0; i < 4; i++)
        #pragma unroll
        for (int j = 0; j < 4; j++) acc[i][j] = (f32x4){0.f, 0.f, 0.f, 0.f};

    const int kq = lane >> 4;
    const int fr = lane & 15;

    int r_[2], cq_[2];
    #pragma unroll
    for (int t = 0; t < 2; ++t) {
        int p = (2 * wid + t) * 1024 + lane * 16;
        int v = p >> 6;
        int r = v ^ ((v >> 2) & 1);
        r_[t]  = r;
        cq_[t] = ((p >> 4) & 3) ^ (r & 3);
    }
    const short* pA0  = A  + (size_t)(row0 + r_[0]) * K + cq_[0] * 8;
    const short* pA1  = A  + (size_t)(row0 + r_[1]) * K + cq_[1] * 8;
    const short* pBh0 = Bh + (size_t)(col0 + r_[0]) * K + cq_[0] * 8;
    const short* pBh1 = Bh + (size_t)(col0 + r_[1]) * K + cq_[1] * 8;
    const short* pBl0 = Bl + (size_t)(col0 + r_[0]) * K + cq_[0] * 8;
    const short* pBl1 = Bl + (size_t)(col0 + r_[1]) * K + cq_[1] * 8;
    char* ldsA0  = (char*)sA  + (2 * wid + 0) * 1024;
    char* ldsA1  = (char*)sA  + (2 * wid + 1) * 1024;
    char* ldsBh0 = (char*)sBh + (2 * wid + 0) * 1024;
    char* ldsBh1 = (char*)sBh + (2 * wid + 1) * 1024;
    char* ldsBl0 = (char*)sBl + (2 * wid + 0) * 1024;
    char* ldsBl1 = (char*)sBl + (2 * wid + 1) * 1024;

    for (int kk = 0; kk < K; kk += 32) {
        GLD16(pA0 + kk, ldsA0);
        GLD16(pA1 + kk, ldsA1);
        GLD16(pBh0 + kk, ldsBh0);
        GLD16(pBh1 + kk, ldsBh1);
        GLD16(pBl0 + kk, ldsBl0);
        GLD16(pBl1 + kk, ldsBl1);
        __syncthreads();

        bf16x8 fa[4], fbh[4], fbl[4];
        #pragma unroll
        for (int mf = 0; mf < 4; ++mf) {
            int r  = wm0 + mf * 16 + fr;
            int so = ((r * 64 + kq * 16) ^ ((r & 7) << 4)) >> 1;
            fa[mf] = *reinterpret_cast<const bf16x8*>(sA + so);
        }
        #pragma unroll
        for (int nf = 0; nf < 4; ++nf) {
            int r  = wn0 + nf * 16 + fr;
            int so = ((r * 64 + kq * 16) ^ ((r & 7) << 4)) >> 1;
            fbh[nf] = *reinterpret_cast<const bf16x8*>(sBh + so);
            fbl[nf] = *reinterpret_cast<const bf16x8*>(sBl + so);
        }
        #pragma unroll
        for (int mf = 0; mf < 4; ++mf)
            #pragma unroll
            for (int nf = 0; nf < 4; ++nf) {
                acc[mf][nf] = __builtin_amdgcn_mfma_f32_16x16x32_bf16(fa[mf], fbh[nf], acc[mf][nf], 0, 0, 0);
                acc[mf][nf] = __builtin_amdgcn_mfma_f32_16x16x32_bf16(fa[mf], fbl[nf], acc[mf][nf], 0, 0, 0);
            }
        __syncthreads();
    }

    const int rq = lane >> 4;
    #pragma unroll
    for (int nf = 0; nf < 4; ++nf) {
        int col = col0 + wn0 + nf * 16 + fr;
        if (col >= N) continue;
        float bia = bias[col];
        float g   = bn4[col];
        float be  = bn4[N + col];
        float mu  = bn4[2 * N + col];
        float va  = bn4[3 * N + col];
        float sc  = rsqrtf(va + EPS_) * g;
        #pragma unroll
        for (int mf = 0; mf < 4; ++mf) {
            #pragma unroll
            for (int r = 0; r < 4; ++r) {
                int row = row0 + wm0 + mf * 16 + rq * 4 + r;
                float v = acc[mf][nf][r] + bia;
                v = (v - mu) * sc + be;
                v = fmaxf(v, 0.f);
                if (ADD) v += res[(size_t)row * N + col];
                out[(size_t)row * N + col] = v;
            }
        }
    }
}

// ---------------- pooling + concat -> bf16 feats [NSAMP][3C] ----------------
__global__ __launch_bounds__(256) void k_pool(const float* __restrict__ Hb,
                                              const float* __restrict__ Cen,
                                              short* __restrict__ feats) {
    int n = blockIdx.x;
    for (int c = threadIdx.x; c < C_; c += 256) {
        float s = 0.f, m = -INFINITY;
        #pragma unroll
        for (int j = 0; j < J_; j++) {
            float v = Hb[((size_t)n * J_ + j) * C_ + c];
            s += v;
            m = fmaxf(m, v);
        }
        feats[(size_t)n * 3 * C_ + c]          = (short)f2bf(s * (1.f / (float)J_));
        feats[(size_t)n * 3 * C_ + C_ + c]     = (short)f2bf(m);
        feats[(size_t)n * 3 * C_ + 2 * C_ + c] = (short)f2bf(Cen[(size_t)n * C_ + c]);
    }
}

// ---------------- final projection ----------------
__global__ __launch_bounds__(256) void k_final(const float* __restrict__ P,
                                               const float* __restrict__ W2,
                                               const float* __restrict__ b2,
                                               float* __restrict__ out) {
    int g = blockIdx.x * 256 + threadIdx.x;
    if (g >= NSAMP * 2 * J_) return;
    int m = g / (2 * J_);
    int o = g % (2 * J_);
    const float* pr = P + (size_t)m * C_;
    const float* wr = W2 + (size_t)o * C_;
    float s = 0.f;
    for (int k = 0; k < C_; k += 4) {
        s = fmaf(pr[k + 0], wr[k + 0], s);
        s = fmaf(pr[k + 1], wr[k + 1], s);
        s = fmaf(pr[k + 2], wr[k + 2], s);
        s = fmaf(pr[k + 3], wr[k + 3], s);
    }
    out[g] = s + b2[o];
}

extern "C" void kernel_launch(void* const* d_in, const int* in_sizes, int n_in,
                              void* d_out, int out_size, void* d_ws, size_t ws_size,
                              hipStream_t stream) {
    const float* features = (const float*)d_in[0];
    const float* coords   = (const float*)d_in[1];
    const int*   center   = (const int*)d_in[2];
    const float* adj      = (const float*)d_in[3];
    const float* Wh       = (const float*)d_in[4];
    const float* bh       = (const float*)d_in[5];
    const float* bn_head  = (const float*)d_in[6];
    const float* Wres     = (const float*)d_in[7];
    const float* bres     = (const float*)d_in[8];
    const float* bn_res   = (const float*)d_in[9];
    const float* Wp1      = (const float*)d_in[10];
    const float* bp1      = (const float*)d_in[11];
    const float* bn_pred  = (const float*)d_in[12];
    const float* Wp2      = (const float*)d_in[13];
    const float* bp2      = (const float*)d_in[14];
    float* out = (float*)d_out;

    // ---- workspace layout ----
    char* ws = (char*)d_ws;
    short* nhwc  = (short*)ws;   ws += (size_t)B_ * HW_ * C_ * 2;     // bf16 NHWC (240 MB)
    float* bufX  = (float*)ws;   ws += (size_t)MROWS * C_ * 4;        // f32 [MROWS,C]
    float* bufH  = (float*)ws;   ws += (size_t)MROWS * C_ * 4;
    short* AhB   = (short*)ws;   ws += (size_t)MROWS * C_ * 2;        // bf16 A
    float* bufC  = (float*)ws;   ws += (size_t)NSAMP * C_ * 4;
    short* featsB= (short*)ws;   ws += (size_t)NSAMP * 3 * C_ * 2;    // bf16 feats
    float* bufP  = (float*)ws;   ws += (size_t)NSAMP * C_ * 4;
    short* WtH   = (short*)ws;   ws += (size_t)NMAT * NPAD * C_ * 2;  // padded [512][480]
    short* WtL   = (short*)ws;   ws += (size_t)NMAT * NPAD * C_ * 2;
    short* WpH   = (short*)ws;   ws += (size_t)NPAD * 3 * C_ * 2;     // padded [512][1440]
    short* WpL   = (short*)ws;   ws += (size_t)NPAD * 3 * C_ * 2;

    dim3 gg(4, MROWS / 128);
    dim3 gp(4, NSAMP / 128);
    dim3 gt(HW_ / TS, C_ / TC, B_);   // 256 x 5 x 16 transpose tiles

    int wtot = NMAT * NPAD * C_ + NPAD * 3 * C_;
    k_wsplit<<<(wtot + 255) / 256, 256, 0, stream>>>(Wh, Wres, Wp1, WtH, WtL, WpH, WpL);
    k_nhwc<<<gt, 256, 0, stream>>>(features, nhwc);
    k_center<<<NSAMP, 256, 0, stream>>>(nhwc, center, bufC);

    // head block: fused gather+mix -> bf16 A, then GEMM
    k_gather_mix<<<NSAMP, 256, 0, stream>>>(nhwc, coords, adj, AhB);
    k_gemm_mfma<false><<<gg, 256, 0, stream>>>(AhB, WtH, WtL, bh, bn_head,
                                               nullptr, bufH, MROWS, C_, C_);

    for (int i = 0; i < L_; i++) {
        int m1 = 1 + 2 * i, m2 = 2 + 2 * i;
        k_mix_bf16<<<NSAMP, 256, 0, stream>>>(bufH, adj, AhB);
        k_gemm_mfma<false><<<gg, 256, 0, stream>>>(
            AhB, WtH + (size_t)m1 * NPAD * C_, WtL + (size_t)m1 * NPAD * C_,
            bres + (size_t)(2 * i) * C_, bn_res + (size_t)(2 * i) * 4 * C_,
            nullptr, bufX, MROWS, C_, C_);
        k_mix_bf16<<<NSAMP, 256, 0, stream>>>(bufX, adj, AhB);
        k_gemm_mfma<true><<<gg, 256, 0, stream>>>(
            AhB, WtH + (size_t)m2 * NPAD * C_, WtL + (size_t)m2 * NPAD * C_,
            bres + (size_t)(2 * i + 1) * C_, bn_res + (size_t)(2 * i + 1) * 4 * C_,
            bufH, bufH, MROWS, C_, C_);
    }

    k_pool<<<NSAMP, 256, 0, stream>>>(bufH, bufC, featsB);

    // pred: relu(bn(feats @ Wp1^T + bp1)); M=1024, N=480, K=1440
    k_gemm_mfma<false><<<gp, 256, 0, stream>>>(featsB, WpH, WpL, bp1, bn_pred,
                                               nullptr, bufP, NSAMP, C_, 3 * C_);

    k_final<<<(NSAMP * 2 * J_ + 255) / 256, 256, 0, stream>>>(bufP, Wp2, bp2, out);
}

// Round 7
// 700.539 us; speedup vs baseline: 1.5717x; 1.4002x over previous
//
#include <hip/hip_runtime.h>
#include <math.h>

#define B_    16
#define NP_   64
#define J_    17
#define C_    480
#define H_    128
#define W_    128
#define L_    4
#define HW_   (H_ * W_)
#define NSAMP (B_ * NP_)      // 1024
#define MROWS (NSAMP * J_)    // 17408
#define EPS_  1e-5f
#define NMAT  (1 + 2 * L_)    // 9 graph-conv weight matrices
#define NPAD  512             // weight N padded to 512 rows (zero-filled) for maskless staging
#define TC    96              // transpose tile: channels
#define TS    64              // transpose tile: spatial

typedef __attribute__((ext_vector_type(8))) short bf16x8;
typedef __attribute__((ext_vector_type(4))) short bf16x4;
typedef __attribute__((ext_vector_type(4))) float f32x4;

__device__ __forceinline__ unsigned short f2bf(float f) {
    unsigned int u = __float_as_uint(f);
    unsigned int r = (u + 0x7fffu + ((u >> 16) & 1u)) >> 16;
    return (unsigned short)r;
}
__device__ __forceinline__ float bf2f(unsigned short h) {
    return __uint_as_float(((unsigned int)h) << 16);
}

// async global->LDS, 16B per lane; LDS dest = base + lane*16 (wave-uniform base)
#define GLD16(gsrc, ldst)                                                                 \
    __builtin_amdgcn_global_load_lds((const __attribute__((address_space(1))) void*)(gsrc), \
                                     (__attribute__((address_space(3))) void*)(ldst), 16, 0, 0)

// ---------------- NCHW f32 -> NHWC bf16 transpose (tiled, both sides coalesced) ----------------
__global__ __launch_bounds__(256) void k_nhwc(const float* __restrict__ feat,
                                              short* __restrict__ nhwc) {
    __shared__ float t[TC][TS + 1];
    int b  = blockIdx.z;
    int c0 = blockIdx.y * TC;
    int s0 = blockIdx.x * TS;
    const float* src = feat + ((size_t)b * C_ + c0) * HW_ + s0;
    int cy = threadIdx.x >> 6;          // 0..3
    int sx = threadIdx.x & 63;
    #pragma unroll
    for (int i = 0; i < TC / 4; ++i) {
        int c = cy + i * 4;
        t[c][sx] = src[(size_t)c * HW_ + sx];
    }
    __syncthreads();
    int sy = threadIdx.x >> 2;                 // 0..63
    int cx = (threadIdx.x & 3) * (TC / 4);     // 0,24,48,72
    short* dst = nhwc + ((size_t)b * HW_ + s0 + sy) * C_ + c0 + cx;
    alignas(16) unsigned short tmp[TC / 4];
    #pragma unroll
    for (int i = 0; i < TC / 4; ++i) tmp[i] = f2bf(t[cx + i][sy]);
    #pragma unroll
    for (int i = 0; i < 3; ++i)
        *reinterpret_cast<uint4*>(dst + i * 8) = *reinterpret_cast<const uint4*>(tmp + i * 8);
}

// ---------------- fused bilinear gather (NHWC bf16) + head adjacency mix -> bf16 A ----------------
__global__ __launch_bounds__(256) void k_gather_mix(const short* __restrict__ nhwc,
                                                    const float* __restrict__ coords,
                                                    const float* __restrict__ adj,
                                                    short* __restrict__ Ah) {
    __shared__ float sX[J_][C_];
    __shared__ float sadj[J_ * J_];
    __shared__ float sw[J_][4];
    __shared__ int   si[J_];
    int n = blockIdx.x;                // 0..NSAMP-1
    int b = n / NP_;
    for (int t = threadIdx.x; t < J_ * J_; t += 256) sadj[t] = adj[t];
    if (threadIdx.x < J_) {
        int j = threadIdx.x;
        int p = n * J_ + j;
        float x = coords[p * 2 + 0];
        float y = coords[p * 2 + 1];
        float x0f = fminf(fmaxf(floorf(x), 0.f), (float)(W_ - 2));
        float y0f = fminf(fmaxf(floorf(y), 0.f), (float)(H_ - 2));
        float wx = x - x0f, wy = y - y0f;
        sw[j][0] = (1.f - wx) * (1.f - wy);
        sw[j][1] = wx * (1.f - wy);
        sw[j][2] = (1.f - wx) * wy;
        sw[j][3] = wx * wy;
        si[j] = (int)y0f * W_ + (int)x0f;
    }
    __syncthreads();
    const short* base = nhwc + (size_t)b * HW_ * C_;
    for (int idx = threadIdx.x; idx < J_ * (C_ / 8); idx += 256) {
        int j  = idx / (C_ / 8);
        int c8 = (idx - j * (C_ / 8)) * 8;
        const short* p00 = base + (size_t)si[j] * C_ + c8;
        bf16x8 v00 = *reinterpret_cast<const bf16x8*>(p00);
        bf16x8 v01 = *reinterpret_cast<const bf16x8*>(p00 + C_);
        bf16x8 v10 = *reinterpret_cast<const bf16x8*>(p00 + W_ * C_);
        bf16x8 v11 = *reinterpret_cast<const bf16x8*>(p00 + W_ * C_ + C_);
        float w0 = sw[j][0], w1 = sw[j][1], w2 = sw[j][2], w3 = sw[j][3];
        #pragma unroll
        for (int e = 0; e < 8; ++e) {
            sX[j][c8 + e] = bf2f((unsigned short)v00[e]) * w0 +
                            bf2f((unsigned short)v01[e]) * w1 +
                            bf2f((unsigned short)v10[e]) * w2 +
                            bf2f((unsigned short)v11[e]) * w3;
        }
    }
    __syncthreads();
    size_t obase = (size_t)n * J_ * C_;
    for (int c = threadIdx.x; c < C_; c += 256) {
        float xv[J_];
        #pragma unroll
        for (int k = 0; k < J_; k++) xv[k] = sX[k][c];
        #pragma unroll
        for (int j = 0; j < J_; j++) {
            float s = 0.f;
            #pragma unroll
            for (int k = 0; k < J_; k++) s += sadj[j * J_ + k] * xv[k];
            Ah[obase + (size_t)j * C_ + c] = (short)f2bf(s);
        }
    }
}

// ---------------- center gather from NHWC ----------------
__global__ __launch_bounds__(256) void k_center(const short* __restrict__ nhwc,
                                                const int* __restrict__ cidx,
                                                float* __restrict__ Cf) {
    int bn = blockIdx.x;
    int b  = bn / NP_;
    int s  = cidx[bn];
    const short* src = nhwc + ((size_t)b * HW_ + s) * C_;
    for (int c = threadIdx.x; c < C_; c += 256)
        Cf[(size_t)bn * C_ + c] = bf2f((unsigned short)src[c]);
}

// ---------------- weight split into padded [NPAD][K] hi/lo bf16 ----------------
__global__ __launch_bounds__(256) void k_wsplit(const float* __restrict__ Wh,
                                                const float* __restrict__ Wres,
                                                const float* __restrict__ Wp1,
                                                short* __restrict__ WtH,
                                                short* __restrict__ WtL,
                                                short* __restrict__ WpH,
                                                short* __restrict__ WpL) {
    int gid = blockIdx.x * 256 + threadIdx.x;
    const int t1 = NMAT * NPAD * C_;
    const int t2 = NPAD * 3 * C_;
    if (gid < t1) {
        int m   = gid / (NPAD * C_);
        int rem = gid % (NPAD * C_);
        int n = rem / C_;
        int k = rem % C_;
        float v = 0.f;
        if (n < C_) {
            const float* src = (m == 0) ? Wh : (Wres + (size_t)(m - 1) * C_ * C_);
            v = src[(size_t)k * C_ + n];
        }
        unsigned short h = f2bf(v);
        WtH[gid] = (short)h;
        WtL[gid] = (short)f2bf(v - bf2f(h));
    } else if (gid < t1 + t2) {
        int g2 = gid - t1;
        int n = g2 / (3 * C_);
        int k = g2 % (3 * C_);
        float v = (n < C_) ? Wp1[(size_t)n * 3 * C_ + k] : 0.f;
        unsigned short h = f2bf(v);
        WpH[g2] = (short)h;
        WpL[g2] = (short)f2bf(v - bf2f(h));
    }
}

// ---------------- adjacency mix on bf16: A[n,j,:] = sum_k adj[j,k] X[n,k,:] ----------------
// 2 samples per block, bf16x4 vectorized. 240 active threads (2 x 120 chunks).
__global__ __launch_bounds__(256) void k_mix_bf16(const short* __restrict__ Xin,
                                                  const float* __restrict__ adj,
                                                  short* __restrict__ Ah) {
    __shared__ float sadj[J_ * J_];
    for (int t = threadIdx.x; t < J_ * J_; t += 256) sadj[t] = adj[t];
    __syncthreads();
    int t = threadIdx.x;
    if (t >= 240) return;
    int n  = blockIdx.x * 2 + (t / 120);
    int c4 = (t % 120) * 4;
    const short* xb = Xin + (size_t)n * J_ * C_ + c4;
    float xf[J_][4];
    #pragma unroll
    for (int k = 0; k < J_; k++) {
        bf16x4 v = *reinterpret_cast<const bf16x4*>(xb + (size_t)k * C_);
        #pragma unroll
        for (int e = 0; e < 4; ++e) xf[k][e] = bf2f((unsigned short)v[e]);
    }
    short* yb = Ah + (size_t)n * J_ * C_ + c4;
    #pragma unroll
    for (int j = 0; j < J_; j++) {
        float a0 = 0.f, a1 = 0.f, a2 = 0.f, a3 = 0.f;
        #pragma unroll
        for (int k = 0; k < J_; k++) {
            float w = sadj[j * J_ + k];
            a0 = fmaf(w, xf[k][0], a0);
            a1 = fmaf(w, xf[k][1], a1);
            a2 = fmaf(w, xf[k][2], a2);
            a3 = fmaf(w, xf[k][3], a3);
        }
        bf16x4 o = {(short)f2bf(a0), (short)f2bf(a1), (short)f2bf(a2), (short)f2bf(a3)};
        *reinterpret_cast<bf16x4*>(yb + (size_t)j * C_) = o;
    }
}

// ---------------- 2-term split MFMA GEMM, gload_lds + 2-phase prefetch + XCD swizzle ----------------
// out[m,n](bf16) = relu(bn(sum_k A[m,k]B[k,n] + bias[n])) (+ res bf16)
// A bf16 [M][K]; B split Bh/Bl bf16 [NPAD][K]. LDS swizzle byte p = (r*64+cq*16)^((r&7)<<4),
// staged linearly by global_load_lds with inverse-swizzled per-lane SOURCE addresses.
// Double-buffered; prefetch issued BEFORE compute; one __syncthreads per k-step (T3 2-phase).
template <bool ADD>
__global__ __launch_bounds__(256) void k_gemm_mfma(const short* __restrict__ A,
                                                   const short* __restrict__ Bh,
                                                   const short* __restrict__ Bl,
                                                   const float* __restrict__ bias,
                                                   const float* __restrict__ bn4,
                                                   const short* res,   // may alias out
                                                   short* out,
                                                   int M, int N, int K) {
    __shared__ short lds[2 * 3 * 4096];   // [buf][sA|sBh|sBl], 48 KB

    // ---- bijective XCD-chunked swizzle (nwg % 8 == 0 guaranteed by caller) ----
    int nwg = gridDim.x * gridDim.y;
    int lin = blockIdx.y * gridDim.x + blockIdx.x;
    int cpx = nwg >> 3;
    int swz = (lin & 7) * cpx + (lin >> 3);
    const int row0 = (swz / gridDim.x) * 128;
    const int col0 = (swz % gridDim.x) * 128;

    const int tid  = threadIdx.x;
    const int lane = tid & 63;
    const int wid  = tid >> 6;
    const int wm0  = (wid >> 1) * 64;
    const int wn0  = (wid & 1) * 64;

    f32x4 acc[4][4];
    #pragma unroll
    for (int i = 0; i < 4; i++)
        #pragma unroll
        for (int j = 0; j < 4; j++) acc[i][j] = (f32x4){0.f, 0.f, 0.f, 0.f};

    const int kq = lane >> 4;
    const int fr = lane & 15;

    // per-lane inverse-swizzle source mapping for this wave's two 1KB staging slices
    int r_[2], cq_[2];
    #pragma unroll
    for (int t = 0; t < 2; ++t) {
        int p = (2 * wid + t) * 1024 + lane * 16;
        int v = p >> 6;
        int r = v ^ ((v >> 2) & 1);
        r_[t]  = r;
        cq_[t] = ((p >> 4) & 3) ^ (r & 3);
    }
    const short* pA0  = A  + (size_t)(row0 + r_[0]) * K + cq_[0] * 8;
    const short* pA1  = A  + (size_t)(row0 + r_[1]) * K + cq_[1] * 8;
    const short* pBh0 = Bh + (size_t)(col0 + r_[0]) * K + cq_[0] * 8;
    const short* pBh1 = Bh + (size_t)(col0 + r_[1]) * K + cq_[1] * 8;
    const short* pBl0 = Bl + (size_t)(col0 + r_[0]) * K + cq_[0] * 8;
    const short* pBl1 = Bl + (size_t)(col0 + r_[1]) * K + cq_[1] * 8;
    const int a0 = (2 * wid + 0) * 1024;    // byte offsets inside one buffer
    const int a1 = (2 * wid + 1) * 1024;

    const int NS = K / 32;
    // prologue: stage tile 0 into buf 0
    {
        char* lb = (char*)lds;
        GLD16(pA0,  lb + a0);        GLD16(pA1,  lb + a1);
        GLD16(pBh0, lb + 8192 + a0); GLD16(pBh1, lb + 8192 + a1);
        GLD16(pBl0, lb + 16384 + a0);GLD16(pBl1, lb + 16384 + a1);
    }
    __syncthreads();

    for (int ks = 0; ks < NS; ++ks) {
        if (ks + 1 < NS) {            // prefetch next tile into other buffer
            const int kk = (ks + 1) * 32;
            char* lb = (char*)lds + ((ks + 1) & 1) * 24576;
            GLD16(pA0 + kk,  lb + a0);        GLD16(pA1 + kk,  lb + a1);
            GLD16(pBh0 + kk, lb + 8192 + a0); GLD16(pBh1 + kk, lb + 8192 + a1);
            GLD16(pBl0 + kk, lb + 16384 + a0);GLD16(pBl1 + kk, lb + 16384 + a1);
        }
        const short* lbc = lds + (ks & 1) * 12288;
        bf16x8 fa[4], fbh[4], fbl[4];
        #pragma unroll
        for (int mf = 0; mf < 4; ++mf) {
            int r  = wm0 + mf * 16 + fr;
            int so = ((r * 64 + kq * 16) ^ ((r & 7) << 4)) >> 1;
            fa[mf] = *reinterpret_cast<const bf16x8*>(lbc + so);
        }
        #pragma unroll
        for (int nf = 0; nf < 4; ++nf) {
            int r  = wn0 + nf * 16 + fr;
            int so = ((r * 64 + kq * 16) ^ ((r & 7) << 4)) >> 1;
            fbh[nf] = *reinterpret_cast<const bf16x8*>(lbc + 4096 + so);
            fbl[nf] = *reinterpret_cast<const bf16x8*>(lbc + 8192 + so);
        }
        __builtin_amdgcn_s_setprio(1);
        #pragma unroll
        for (int mf = 0; mf < 4; ++mf)
            #pragma unroll
            for (int nf = 0; nf < 4; ++nf) {
                acc[mf][nf] = __builtin_amdgcn_mfma_f32_16x16x32_bf16(fa[mf], fbh[nf], acc[mf][nf], 0, 0, 0);
                acc[mf][nf] = __builtin_amdgcn_mfma_f32_16x16x32_bf16(fa[mf], fbl[nf], acc[mf][nf], 0, 0, 0);
            }
        __builtin_amdgcn_s_setprio(0);
        __syncthreads();   // drains prefetch (vmcnt 0) + guards buffer reuse
    }

    // ---- epilogue: C/D layout col=lane&15, row=(lane>>4)*4+reg ----
    const int rq = lane >> 4;
    #pragma unroll
    for (int nf = 0; nf < 4; ++nf) {
        int col = col0 + wn0 + nf * 16 + fr;
        if (col >= N) continue;
        float bia = bias[col];
        float g   = bn4[col];
        float be  = bn4[N + col];
        float mu  = bn4[2 * N + col];
        float va  = bn4[3 * N + col];
        float sc  = rsqrtf(va + EPS_) * g;
        #pragma unroll
        for (int mf = 0; mf < 4; ++mf) {
            #pragma unroll
            for (int r = 0; r < 4; ++r) {
                int row = row0 + wm0 + mf * 16 + rq * 4 + r;
                float v = acc[mf][nf][r] + bia;
                v = (v - mu) * sc + be;
                v = fmaxf(v, 0.f);
                if (ADD) v += bf2f((unsigned short)res[(size_t)row * N + col]);
                out[(size_t)row * N + col] = (short)f2bf(v);
            }
        }
    }
}

// ---------------- pooling + concat -> bf16 feats [NSAMP][3C] ----------------
__global__ __launch_bounds__(256) void k_pool(const short* __restrict__ Hb,
                                              const float* __restrict__ Cen,
                                              short* __restrict__ feats) {
    int n = blockIdx.x;
    for (int c = threadIdx.x; c < C_; c += 256) {
        float s = 0.f, m = -INFINITY;
        #pragma unroll
        for (int j = 0; j < J_; j++) {
            float v = bf2f((unsigned short)Hb[((size_t)n * J_ + j) * C_ + c]);
            s += v;
            m = fmaxf(m, v);
        }
        feats[(size_t)n * 3 * C_ + c]          = (short)f2bf(s * (1.f / (float)J_));
        feats[(size_t)n * 3 * C_ + C_ + c]     = (short)f2bf(m);
        feats[(size_t)n * 3 * C_ + 2 * C_ + c] = (short)f2bf(Cen[(size_t)n * C_ + c]);
    }
}

// ---------------- final projection (P bf16) ----------------
__global__ __launch_bounds__(256) void k_final(const short* __restrict__ P,
                                               const float* __restrict__ W2,
                                               const float* __restrict__ b2,
                                               float* __restrict__ out) {
    int g = blockIdx.x * 256 + threadIdx.x;
    if (g >= NSAMP * 2 * J_) return;
    int m = g / (2 * J_);
    int o = g % (2 * J_);
    const short* pr = P + (size_t)m * C_;
    const float* wr = W2 + (size_t)o * C_;
    float s = 0.f;
    for (int k = 0; k < C_; k += 4) {
        s = fmaf(bf2f((unsigned short)pr[k + 0]), wr[k + 0], s);
        s = fmaf(bf2f((unsigned short)pr[k + 1]), wr[k + 1], s);
        s = fmaf(bf2f((unsigned short)pr[k + 2]), wr[k + 2], s);
        s = fmaf(bf2f((unsigned short)pr[k + 3]), wr[k + 3], s);
    }
    out[g] = s + b2[o];
}

extern "C" void kernel_launch(void* const* d_in, const int* in_sizes, int n_in,
                              void* d_out, int out_size, void* d_ws, size_t ws_size,
                              hipStream_t stream) {
    const float* features = (const float*)d_in[0];
    const float* coords   = (const float*)d_in[1];
    const int*   center   = (const int*)d_in[2];
    const float* adj      = (const float*)d_in[3];
    const float* Wh       = (const float*)d_in[4];
    const float* bh       = (const float*)d_in[5];
    const float* bn_head  = (const float*)d_in[6];
    const float* Wres     = (const float*)d_in[7];
    const float* bres     = (const float*)d_in[8];
    const float* bn_res   = (const float*)d_in[9];
    const float* Wp1      = (const float*)d_in[10];
    const float* bp1      = (const float*)d_in[11];
    const float* bn_pred  = (const float*)d_in[12];
    const float* Wp2      = (const float*)d_in[13];
    const float* bp2      = (const float*)d_in[14];
    float* out = (float*)d_out;

    // ---- workspace layout ----
    char* ws = (char*)d_ws;
    short* nhwc  = (short*)ws;   ws += (size_t)B_ * HW_ * C_ * 2;     // bf16 NHWC (240 MB)
    short* bufX  = (short*)ws;   ws += (size_t)MROWS * C_ * 2;        // bf16 [MROWS,C]
    short* bufH  = (short*)ws;   ws += (size_t)MROWS * C_ * 2;
    short* AhB   = (short*)ws;   ws += (size_t)MROWS * C_ * 2;        // bf16 A
    float* bufC  = (float*)ws;   ws += (size_t)NSAMP * C_ * 4;
    short* featsB= (short*)ws;   ws += (size_t)NSAMP * 3 * C_ * 2;    // bf16 feats
    short* bufP  = (short*)ws;   ws += (size_t)NSAMP * C_ * 2;        // bf16 pred
    short* WtH   = (short*)ws;   ws += (size_t)NMAT * NPAD * C_ * 2;  // padded [512][480]
    short* WtL   = (short*)ws;   ws += (size_t)NMAT * NPAD * C_ * 2;
    short* WpH   = (short*)ws;   ws += (size_t)NPAD * 3 * C_ * 2;     // padded [512][1440]
    short* WpL   = (short*)ws;   ws += (size_t)NPAD * 3 * C_ * 2;

    dim3 gg(4, MROWS / 128);          // 544 blocks (544 % 8 == 0)
    dim3 gp(4, NSAMP / 128);          // 32 blocks  (32 % 8 == 0)
    dim3 gt(HW_ / TS, C_ / TC, B_);   // transpose tiles

    int wtot = NMAT * NPAD * C_ + NPAD * 3 * C_;
    k_wsplit<<<(wtot + 255) / 256, 256, 0, stream>>>(Wh, Wres, Wp1, WtH, WtL, WpH, WpL);
    k_nhwc<<<gt, 256, 0, stream>>>(features, nhwc);
    k_center<<<NSAMP, 256, 0, stream>>>(nhwc, center, bufC);

    // head block
    k_gather_mix<<<NSAMP, 256, 0, stream>>>(nhwc, coords, adj, AhB);
    k_gemm_mfma<false><<<gg, 256, 0, stream>>>(AhB, WtH, WtL, bh, bn_head,
                                               nullptr, bufH, MROWS, C_, C_);

    for (int i = 0; i < L_; i++) {
        int m1 = 1 + 2 * i, m2 = 2 + 2 * i;
        k_mix_bf16<<<NSAMP / 2, 256, 0, stream>>>(bufH, adj, AhB);
        k_gemm_mfma<false><<<gg, 256, 0, stream>>>(
            AhB, WtH + (size_t)m1 * NPAD * C_, WtL + (size_t)m1 * NPAD * C_,
            bres + (size_t)(2 * i) * C_, bn_res + (size_t)(2 * i) * 4 * C_,
            nullptr, bufX, MROWS, C_, C_);
        k_mix_bf16<<<NSAMP / 2, 256, 0, stream>>>(bufX, adj, AhB);
        k_gemm_mfma<true><<<gg, 256, 0, stream>>>(
            AhB, WtH + (size_t)m2 * NPAD * C_, WtL + (size_t)m2 * NPAD * C_,
            bres + (size_t)(2 * i + 1) * C_, bn_res + (size_t)(2 * i + 1) * 4 * C_,
            bufH, bufH, MROWS, C_, C_);
    }

    k_pool<<<NSAMP, 256, 0, stream>>>(bufH, bufC, featsB);

    // pred: relu(bn(feats @ Wp1^T + bp1)); M=1024, N=480, K=1440
    k_gemm_mfma<false><<<gp, 256, 0, stream>>>(featsB, WpH, WpL, bp1, bn_pred,
                                               nullptr, bufP, NSAMP, C_, 3 * C_);

    k_final<<<(NSAMP * 2 * J_ + 255) / 256, 256, 0, stream>>>(bufP, Wp2, bp2, out);
}

// Round 8
// 624.376 us; speedup vs baseline: 1.7634x; 1.1220x over previous
//
#include <hip/hip_runtime.h>
#include <math.h>

#define B_    16
#define NP_   64
#define J_    17
#define C_    480
#define H_    128
#define W_    128
#define L_    4
#define HW_   (H_ * W_)
#define NSAMP (B_ * NP_)      // 1024
#define MROWS (NSAMP * J_)    // 17408
#define EPS_  1e-5f
#define NMAT  (1 + 2 * L_)    // 9 graph-conv weight matrices
#define NPAD  512             // weight N padded to 512 rows (zero-filled) for maskless staging
#define TC    96              // transpose tile: channels
#define TS    64              // transpose tile: spatial

typedef __attribute__((ext_vector_type(8))) short bf16x8;
typedef __attribute__((ext_vector_type(4))) short bf16x4;
typedef __attribute__((ext_vector_type(4))) float f32x4;

__device__ __forceinline__ unsigned short f2bf(float f) {
    unsigned int u = __float_as_uint(f);
    unsigned int r = (u + 0x7fffu + ((u >> 16) & 1u)) >> 16;
    return (unsigned short)r;
}
__device__ __forceinline__ float bf2f(unsigned short h) {
    return __uint_as_float(((unsigned int)h) << 16);
}

// async global->LDS, 16B per lane; LDS dest = base + lane*16 (wave-uniform base)
#define GLD16(gsrc, ldst)                                                                 \
    __builtin_amdgcn_global_load_lds((const __attribute__((address_space(1))) void*)(gsrc), \
                                     (__attribute__((address_space(3))) void*)(ldst), 16, 0, 0)

// ---------------- NCHW f32 -> NHWC bf16 transpose (tiled, both sides coalesced) ----------------
__global__ __launch_bounds__(256) void k_nhwc(const float* __restrict__ feat,
                                              short* __restrict__ nhwc) {
    __shared__ float t[TC][TS + 1];
    int b  = blockIdx.z;
    int c0 = blockIdx.y * TC;
    int s0 = blockIdx.x * TS;
    const float* src = feat + ((size_t)b * C_ + c0) * HW_ + s0;
    int cy = threadIdx.x >> 6;          // 0..3
    int sx = threadIdx.x & 63;
    #pragma unroll
    for (int i = 0; i < TC / 4; ++i) {
        int c = cy + i * 4;
        t[c][sx] = src[(size_t)c * HW_ + sx];
    }
    __syncthreads();
    int sy = threadIdx.x >> 2;                 // 0..63
    int cx = (threadIdx.x & 3) * (TC / 4);     // 0,24,48,72
    short* dst = nhwc + ((size_t)b * HW_ + s0 + sy) * C_ + c0 + cx;
    alignas(16) unsigned short tmp[TC / 4];
    #pragma unroll
    for (int i = 0; i < TC / 4; ++i) tmp[i] = f2bf(t[cx + i][sy]);
    #pragma unroll
    for (int i = 0; i < 3; ++i)
        *reinterpret_cast<uint4*>(dst + i * 8) = *reinterpret_cast<const uint4*>(tmp + i * 8);
}

// ---------------- fused bilinear gather (NHWC bf16) + head adjacency mix -> bf16 A ----------------
__global__ __launch_bounds__(256) void k_gather_mix(const short* __restrict__ nhwc,
                                                    const float* __restrict__ coords,
                                                    const float* __restrict__ adj,
                                                    short* __restrict__ Ah) {
    __shared__ float sX[J_][C_];
    __shared__ float sadj[J_ * J_];
    __shared__ float sw[J_][4];
    __shared__ int   si[J_];
    int n = blockIdx.x;                // 0..NSAMP-1
    int b = n / NP_;
    for (int t = threadIdx.x; t < J_ * J_; t += 256) sadj[t] = adj[t];
    if (threadIdx.x < J_) {
        int j = threadIdx.x;
        int p = n * J_ + j;
        float x = coords[p * 2 + 0];
        float y = coords[p * 2 + 1];
        float x0f = fminf(fmaxf(floorf(x), 0.f), (float)(W_ - 2));
        float y0f = fminf(fmaxf(floorf(y), 0.f), (float)(H_ - 2));
        float wx = x - x0f, wy = y - y0f;
        sw[j][0] = (1.f - wx) * (1.f - wy);
        sw[j][1] = wx * (1.f - wy);
        sw[j][2] = (1.f - wx) * wy;
        sw[j][3] = wx * wy;
        si[j] = (int)y0f * W_ + (int)x0f;
    }
    __syncthreads();
    const short* base = nhwc + (size_t)b * HW_ * C_;
    for (int idx = threadIdx.x; idx < J_ * (C_ / 8); idx += 256) {
        int j  = idx / (C_ / 8);
        int c8 = (idx - j * (C_ / 8)) * 8;
        const short* p00 = base + (size_t)si[j] * C_ + c8;
        bf16x8 v00 = *reinterpret_cast<const bf16x8*>(p00);
        bf16x8 v01 = *reinterpret_cast<const bf16x8*>(p00 + C_);
        bf16x8 v10 = *reinterpret_cast<const bf16x8*>(p00 + W_ * C_);
        bf16x8 v11 = *reinterpret_cast<const bf16x8*>(p00 + W_ * C_ + C_);
        float w0 = sw[j][0], w1 = sw[j][1], w2 = sw[j][2], w3 = sw[j][3];
        #pragma unroll
        for (int e = 0; e < 8; ++e) {
            sX[j][c8 + e] = bf2f((unsigned short)v00[e]) * w0 +
                            bf2f((unsigned short)v01[e]) * w1 +
                            bf2f((unsigned short)v10[e]) * w2 +
                            bf2f((unsigned short)v11[e]) * w3;
        }
    }
    __syncthreads();
    size_t obase = (size_t)n * J_ * C_;
    for (int c = threadIdx.x; c < C_; c += 256) {
        float xv[J_];
        #pragma unroll
        for (int k = 0; k < J_; k++) xv[k] = sX[k][c];
        #pragma unroll
        for (int j = 0; j < J_; j++) {
            float s = 0.f;
            #pragma unroll
            for (int k = 0; k < J_; k++) s += sadj[j * J_ + k] * xv[k];
            Ah[obase + (size_t)j * C_ + c] = (short)f2bf(s);
        }
    }
}

// ---------------- weight -> single bf16, padded [NPAD][K] ----------------
// conv: W[k][n] -> Wt[m][n][k] (transpose); pred: Wp1[n][k] direct; rows n>=C_ zeroed.
__global__ __launch_bounds__(256) void k_wsplit(const float* __restrict__ Wh,
                                                const float* __restrict__ Wres,
                                                const float* __restrict__ Wp1,
                                                short* __restrict__ WtH,
                                                short* __restrict__ WpH) {
    int gid = blockIdx.x * 256 + threadIdx.x;
    const int t1 = NMAT * NPAD * C_;
    const int t2 = NPAD * 3 * C_;
    if (gid < t1) {
        int m   = gid / (NPAD * C_);
        int rem = gid % (NPAD * C_);
        int n = rem / C_;
        int k = rem % C_;
        float v = 0.f;
        if (n < C_) {
            const float* src = (m == 0) ? Wh : (Wres + (size_t)(m - 1) * C_ * C_);
            v = src[(size_t)k * C_ + n];
        }
        WtH[gid] = (short)f2bf(v);
    } else if (gid < t1 + t2) {
        int g2 = gid - t1;
        int n = g2 / (3 * C_);
        int k = g2 % (3 * C_);
        float v = (n < C_) ? Wp1[(size_t)n * 3 * C_ + k] : 0.f;
        WpH[g2] = (short)f2bf(v);
    }
}

// ---------------- adjacency mix on bf16: A[n,j,:] = sum_k adj[j,k] X[n,k,:] ----------------
__global__ __launch_bounds__(256) void k_mix_bf16(const short* __restrict__ Xin,
                                                  const float* __restrict__ adj,
                                                  short* __restrict__ Ah) {
    __shared__ float sadj[J_ * J_];
    for (int t = threadIdx.x; t < J_ * J_; t += 256) sadj[t] = adj[t];
    __syncthreads();
    int t = threadIdx.x;
    if (t >= 240) return;
    int n  = blockIdx.x * 2 + (t / 120);
    int c4 = (t % 120) * 4;
    const short* xb = Xin + (size_t)n * J_ * C_ + c4;
    float xf[J_][4];
    #pragma unroll
    for (int k = 0; k < J_; k++) {
        bf16x4 v = *reinterpret_cast<const bf16x4*>(xb + (size_t)k * C_);
        #pragma unroll
        for (int e = 0; e < 4; ++e) xf[k][e] = bf2f((unsigned short)v[e]);
    }
    short* yb = Ah + (size_t)n * J_ * C_ + c4;
    #pragma unroll
    for (int j = 0; j < J_; j++) {
        float a0 = 0.f, a1 = 0.f, a2 = 0.f, a3 = 0.f;
        #pragma unroll
        for (int k = 0; k < J_; k++) {
            float w = sadj[j * J_ + k];
            a0 = fmaf(w, xf[k][0], a0);
            a1 = fmaf(w, xf[k][1], a1);
            a2 = fmaf(w, xf[k][2], a2);
            a3 = fmaf(w, xf[k][3], a3);
        }
        bf16x4 o = {(short)f2bf(a0), (short)f2bf(a1), (short)f2bf(a2), (short)f2bf(a3)};
        *reinterpret_cast<bf16x4*>(yb + (size_t)j * C_) = o;
    }
}

// ---------------- 1-term bf16 MFMA GEMM, gload_lds + 2-phase prefetch + XCD swizzle ----------------
// out[m,n](bf16) = relu(bn(sum_k A[m,k]B[k,n] + bias[n])) (+ res bf16)
// A bf16 [M][K]; B bf16 [NPAD][K]. LDS swizzle byte p = (r*64+cq*16)^((r&7)<<4), staged
// linearly by global_load_lds with inverse-swizzled per-lane SOURCE addresses.
template <bool ADD>
__global__ __launch_bounds__(256) void k_gemm_mfma(const short* __restrict__ A,
                                                   const short* __restrict__ Bm,
                                                   const float* __restrict__ bias,
                                                   const float* __restrict__ bn4,
                                                   const short* res,   // may alias out
                                                   short* out,
                                                   int M, int N, int K) {
    __shared__ short lds[2 * 2 * 4096];   // [buf][sA|sB], 32 KB

    // bijective XCD-chunked swizzle (nwg % 8 == 0 guaranteed by caller)
    int nwg = gridDim.x * gridDim.y;
    int lin = blockIdx.y * gridDim.x + blockIdx.x;
    int cpx = nwg >> 3;
    int swz = (lin & 7) * cpx + (lin >> 3);
    const int row0 = (swz / gridDim.x) * 128;
    const int col0 = (swz % gridDim.x) * 128;

    const int tid  = threadIdx.x;
    const int lane = tid & 63;
    const int wid  = tid >> 6;
    const int wm0  = (wid >> 1) * 64;
    const int wn0  = (wid & 1) * 64;

    f32x4 acc[4][4];
    #pragma unroll
    for (int i = 0; i < 4; i++)
        #pragma unroll
        for (int j = 0; j < 4; j++) acc[i][j] = (f32x4){0.f, 0.f, 0.f, 0.f};

    const int kq = lane >> 4;
    const int fr = lane & 15;

    // per-lane inverse-swizzle source mapping for this wave's two 1KB staging slices
    int r_[2], cq_[2];
    #pragma unroll
    for (int t = 0; t < 2; ++t) {
        int p = (2 * wid + t) * 1024 + lane * 16;
        int v = p >> 6;
        int r = v ^ ((v >> 2) & 1);
        r_[t]  = r;
        cq_[t] = ((p >> 4) & 3) ^ (r & 3);
    }
    const short* pA0 = A  + (size_t)(row0 + r_[0]) * K + cq_[0] * 8;
    const short* pA1 = A  + (size_t)(row0 + r_[1]) * K + cq_[1] * 8;
    const short* pB0 = Bm + (size_t)(col0 + r_[0]) * K + cq_[0] * 8;
    const short* pB1 = Bm + (size_t)(col0 + r_[1]) * K + cq_[1] * 8;
    const int a0 = (2 * wid + 0) * 1024;    // byte offsets inside one buffer
    const int a1 = (2 * wid + 1) * 1024;

    const int NS = K / 32;
    {   // prologue: stage tile 0 into buf 0
        char* lb = (char*)lds;
        GLD16(pA0, lb + a0);        GLD16(pA1, lb + a1);
        GLD16(pB0, lb + 8192 + a0); GLD16(pB1, lb + 8192 + a1);
    }
    __syncthreads();

    for (int ks = 0; ks < NS; ++ks) {
        if (ks + 1 < NS) {            // prefetch next tile into other buffer
            const int kk = (ks + 1) * 32;
            char* lb = (char*)lds + ((ks + 1) & 1) * 16384;
            GLD16(pA0 + kk, lb + a0);        GLD16(pA1 + kk, lb + a1);
            GLD16(pB0 + kk, lb + 8192 + a0); GLD16(pB1 + kk, lb + 8192 + a1);
        }
        const short* lbc = lds + (ks & 1) * 8192;
        bf16x8 fa[4], fb[4];
        #pragma unroll
        for (int mf = 0; mf < 4; ++mf) {
            int r  = wm0 + mf * 16 + fr;
            int so = ((r * 64 + kq * 16) ^ ((r & 7) << 4)) >> 1;
            fa[mf] = *reinterpret_cast<const bf16x8*>(lbc + so);
        }
        #pragma unroll
        for (int nf = 0; nf < 4; ++nf) {
            int r  = wn0 + nf * 16 + fr;
            int so = ((r * 64 + kq * 16) ^ ((r & 7) << 4)) >> 1;
            fb[nf] = *reinterpret_cast<const bf16x8*>(lbc + 4096 + so);
        }
        __builtin_amdgcn_s_setprio(1);
        #pragma unroll
        for (int mf = 0; mf < 4; ++mf)
            #pragma unroll
            for (int nf = 0; nf < 4; ++nf)
                acc[mf][nf] = __builtin_amdgcn_mfma_f32_16x16x32_bf16(fa[mf], fb[nf], acc[mf][nf], 0, 0, 0);
        __builtin_amdgcn_s_setprio(0);
        __syncthreads();   // drains prefetch (vmcnt 0) + guards buffer reuse
    }

    // ---- epilogue: C/D layout col=lane&15, row=(lane>>4)*4+reg ----
    const int rq = lane >> 4;
    #pragma unroll
    for (int nf = 0; nf < 4; ++nf) {
        int col = col0 + wn0 + nf * 16 + fr;
        if (col >= N) continue;
        float bia = bias[col];
        float g   = bn4[col];
        float be  = bn4[N + col];
        float mu  = bn4[2 * N + col];
        float va  = bn4[3 * N + col];
        float sc  = rsqrtf(va + EPS_) * g;
        #pragma unroll
        for (int mf = 0; mf < 4; ++mf) {
            #pragma unroll
            for (int r = 0; r < 4; ++r) {
                int row = row0 + wm0 + mf * 16 + rq * 4 + r;
                float v = acc[mf][nf][r] + bia;
                v = (v - mu) * sc + be;
                v = fmaxf(v, 0.f);
                if (ADD) v += bf2f((unsigned short)res[(size_t)row * N + col]);
                out[(size_t)row * N + col] = (short)f2bf(v);
            }
        }
    }
}

// ---------------- pooling + concat (+center direct from NHWC) -> bf16 feats [NSAMP][3C] ----------------
__global__ __launch_bounds__(256) void k_pool(const short* __restrict__ Hb,
                                              const short* __restrict__ nhwc,
                                              const int* __restrict__ cidx,
                                              short* __restrict__ feats) {
    int n = blockIdx.x;
    int b = n / NP_;
    const short* cen = nhwc + ((size_t)b * HW_ + cidx[n]) * C_;
    for (int c = threadIdx.x; c < C_; c += 256) {
        float s = 0.f, m = -INFINITY;
        #pragma unroll
        for (int j = 0; j < J_; j++) {
            float v = bf2f((unsigned short)Hb[((size_t)n * J_ + j) * C_ + c]);
            s += v;
            m = fmaxf(m, v);
        }
        feats[(size_t)n * 3 * C_ + c]          = (short)f2bf(s * (1.f / (float)J_));
        feats[(size_t)n * 3 * C_ + C_ + c]     = (short)f2bf(m);
        feats[(size_t)n * 3 * C_ + 2 * C_ + c] = cen[c];
    }
}

// ---------------- final projection (P bf16) ----------------
__global__ __launch_bounds__(256) void k_final(const short* __restrict__ P,
                                               const float* __restrict__ W2,
                                               const float* __restrict__ b2,
                                               float* __restrict__ out) {
    int g = blockIdx.x * 256 + threadIdx.x;
    if (g >= NSAMP * 2 * J_) return;
    int m = g / (2 * J_);
    int o = g % (2 * J_);
    const short* pr = P + (size_t)m * C_;
    const float* wr = W2 + (size_t)o * C_;
    float s = 0.f;
    for (int k = 0; k < C_; k += 4) {
        s = fmaf(bf2f((unsigned short)pr[k + 0]), wr[k + 0], s);
        s = fmaf(bf2f((unsigned short)pr[k + 1]), wr[k + 1], s);
        s = fmaf(bf2f((unsigned short)pr[k + 2]), wr[k + 2], s);
        s = fmaf(bf2f((unsigned short)pr[k + 3]), wr[k + 3], s);
    }
    out[g] = s + b2[o];
}

extern "C" void kernel_launch(void* const* d_in, const int* in_sizes, int n_in,
                              void* d_out, int out_size, void* d_ws, size_t ws_size,
                              hipStream_t stream) {
    const float* features = (const float*)d_in[0];
    const float* coords   = (const float*)d_in[1];
    const int*   center   = (const int*)d_in[2];
    const float* adj      = (const float*)d_in[3];
    const float* Wh       = (const float*)d_in[4];
    const float* bh       = (const float*)d_in[5];
    const float* bn_head  = (const float*)d_in[6];
    const float* Wres     = (const float*)d_in[7];
    const float* bres     = (const float*)d_in[8];
    const float* bn_res   = (const float*)d_in[9];
    const float* Wp1      = (const float*)d_in[10];
    const float* bp1      = (const float*)d_in[11];
    const float* bn_pred  = (const float*)d_in[12];
    const float* Wp2      = (const float*)d_in[13];
    const float* bp2      = (const float*)d_in[14];
    float* out = (float*)d_out;

    // ---- workspace layout ----
    char* ws = (char*)d_ws;
    short* nhwc  = (short*)ws;   ws += (size_t)B_ * HW_ * C_ * 2;     // bf16 NHWC (~252 MB)
    short* bufX  = (short*)ws;   ws += (size_t)MROWS * C_ * 2;        // bf16 [MROWS,C]
    short* bufH  = (short*)ws;   ws += (size_t)MROWS * C_ * 2;
    short* AhB   = (short*)ws;   ws += (size_t)MROWS * C_ * 2;        // bf16 A
    short* featsB= (short*)ws;   ws += (size_t)NSAMP * 3 * C_ * 2;    // bf16 feats
    short* bufP  = (short*)ws;   ws += (size_t)NSAMP * C_ * 2;        // bf16 pred
    short* WtH   = (short*)ws;   ws += (size_t)NMAT * NPAD * C_ * 2;  // padded [512][480]
    short* WpH   = (short*)ws;   ws += (size_t)NPAD * 3 * C_ * 2;     // padded [512][1440]

    dim3 gg(4, MROWS / 128);          // 544 blocks (544 % 8 == 0)
    dim3 gp(4, NSAMP / 128);          // 32 blocks  (32 % 8 == 0)
    dim3 gt(HW_ / TS, C_ / TC, B_);   // transpose tiles

    int wtot = NMAT * NPAD * C_ + NPAD * 3 * C_;
    k_wsplit<<<(wtot + 255) / 256, 256, 0, stream>>>(Wh, Wres, Wp1, WtH, WpH);
    k_nhwc<<<gt, 256, 0, stream>>>(features, nhwc);

    // head block
    k_gather_mix<<<NSAMP, 256, 0, stream>>>(nhwc, coords, adj, AhB);
    k_gemm_mfma<false><<<gg, 256, 0, stream>>>(AhB, WtH, bh, bn_head,
                                               nullptr, bufH, MROWS, C_, C_);

    for (int i = 0; i < L_; i++) {
        int m1 = 1 + 2 * i, m2 = 2 + 2 * i;
        k_mix_bf16<<<NSAMP / 2, 256, 0, stream>>>(bufH, adj, AhB);
        k_gemm_mfma<false><<<gg, 256, 0, stream>>>(
            AhB, WtH + (size_t)m1 * NPAD * C_,
            bres + (size_t)(2 * i) * C_, bn_res + (size_t)(2 * i) * 4 * C_,
            nullptr, bufX, MROWS, C_, C_);
        k_mix_bf16<<<NSAMP / 2, 256, 0, stream>>>(bufX, adj, AhB);
        k_gemm_mfma<true><<<gg, 256, 0, stream>>>(
            AhB, WtH + (size_t)m2 * NPAD * C_,
            bres + (size_t)(2 * i + 1) * C_, bn_res + (size_t)(2 * i + 1) * 4 * C_,
            bufH, bufH, MROWS, C_, C_);
    }

    k_pool<<<NSAMP, 256, 0, stream>>>(bufH, nhwc, center, featsB);

    // pred: relu(bn(feats @ Wp1^T + bp1)); M=1024, N=480, K=1440
    k_gemm_mfma<false><<<gp, 256, 0, stream>>>(featsB, WpH, bp1, bn_pred,
                                               nullptr, bufP, NSAMP, C_, 3 * C_);

    k_final<<<(NSAMP * 2 * J_ + 255) / 256, 256, 0, stream>>>(bufP, Wp2, bp2, out);
}

// Round 9
// 621.708 us; speedup vs baseline: 1.7709x; 1.0043x over previous
//
#include <hip/hip_runtime.h>
#include <math.h>

#define B_    16
#define NP_   64
#define J_    17
#define C_    480
#define H_    128
#define W_    128
#define L_    4
#define HW_   (H_ * W_)
#define NSAMP (B_ * NP_)      // 1024
#define MROWS (NSAMP * J_)    // 17408
#define EPS_  1e-5f
#define NMAT  (1 + 2 * L_)    // 9 graph-conv weight matrices
#define NPAD  512             // weight N padded to 512 rows (zero-filled) for maskless staging
#define TC    96              // transpose tile: channels
#define TS    64              // transpose tile: spatial

typedef __attribute__((ext_vector_type(8))) short bf16x8;
typedef __attribute__((ext_vector_type(4))) short bf16x4;
typedef __attribute__((ext_vector_type(4))) float f32x4;

__device__ __forceinline__ unsigned short f2bf(float f) {
    unsigned int u = __float_as_uint(f);
    unsigned int r = (u + 0x7fffu + ((u >> 16) & 1u)) >> 16;
    return (unsigned short)r;
}
__device__ __forceinline__ float bf2f(unsigned short h) {
    return __uint_as_float(((unsigned int)h) << 16);
}

// async global->LDS, 16B per lane; LDS dest = base + lane*16 (wave-uniform base)
#define GLD16(gsrc, ldst)                                                                 \
    __builtin_amdgcn_global_load_lds((const __attribute__((address_space(1))) void*)(gsrc), \
                                     (__attribute__((address_space(3))) void*)(ldst), 16, 0, 0)

// ---------------- NCHW f32 -> NHWC bf16 transpose (tiled, both sides coalesced) ----------------
__global__ __launch_bounds__(256) void k_nhwc(const float* __restrict__ feat,
                                              short* __restrict__ nhwc) {
    __shared__ float t[TC][TS + 1];
    int b  = blockIdx.z;
    int c0 = blockIdx.y * TC;
    int s0 = blockIdx.x * TS;
    const float* src = feat + ((size_t)b * C_ + c0) * HW_ + s0;
    int cy = threadIdx.x >> 6;          // 0..3
    int sx = threadIdx.x & 63;
    #pragma unroll
    for (int i = 0; i < TC / 4; ++i) {
        int c = cy + i * 4;
        t[c][sx] = src[(size_t)c * HW_ + sx];
    }
    __syncthreads();
    int sy = threadIdx.x >> 2;                 // 0..63
    int cx = (threadIdx.x & 3) * (TC / 4);     // 0,24,48,72
    short* dst = nhwc + ((size_t)b * HW_ + s0 + sy) * C_ + c0 + cx;
    alignas(16) unsigned short tmp[TC / 4];
    #pragma unroll
    for (int i = 0; i < TC / 4; ++i) tmp[i] = f2bf(t[cx + i][sy]);
    #pragma unroll
    for (int i = 0; i < 3; ++i)
        *reinterpret_cast<uint4*>(dst + i * 8) = *reinterpret_cast<const uint4*>(tmp + i * 8);
}

// ---------------- fused bilinear gather (NHWC bf16) + head adjacency mix -> bf16 A ----------------
__global__ __launch_bounds__(256) void k_gather_mix(const short* __restrict__ nhwc,
                                                    const float* __restrict__ coords,
                                                    const float* __restrict__ adj,
                                                    short* __restrict__ Ah) {
    __shared__ float sX[J_][C_];
    __shared__ float sadj[J_ * J_];
    __shared__ float sw[J_][4];
    __shared__ int   si[J_];
    int n = blockIdx.x;                // 0..NSAMP-1
    int b = n / NP_;
    for (int t = threadIdx.x; t < J_ * J_; t += 256) sadj[t] = adj[t];
    if (threadIdx.x < J_) {
        int j = threadIdx.x;
        int p = n * J_ + j;
        float x = coords[p * 2 + 0];
        float y = coords[p * 2 + 1];
        float x0f = fminf(fmaxf(floorf(x), 0.f), (float)(W_ - 2));
        float y0f = fminf(fmaxf(floorf(y), 0.f), (float)(H_ - 2));
        float wx = x - x0f, wy = y - y0f;
        sw[j][0] = (1.f - wx) * (1.f - wy);
        sw[j][1] = wx * (1.f - wy);
        sw[j][2] = (1.f - wx) * wy;
        sw[j][3] = wx * wy;
        si[j] = (int)y0f * W_ + (int)x0f;
    }
    __syncthreads();
    const short* base = nhwc + (size_t)b * HW_ * C_;
    for (int idx = threadIdx.x; idx < J_ * (C_ / 8); idx += 256) {
        int j  = idx / (C_ / 8);
        int c8 = (idx - j * (C_ / 8)) * 8;
        const short* p00 = base + (size_t)si[j] * C_ + c8;
        bf16x8 v00 = *reinterpret_cast<const bf16x8*>(p00);
        bf16x8 v01 = *reinterpret_cast<const bf16x8*>(p00 + C_);
        bf16x8 v10 = *reinterpret_cast<const bf16x8*>(p00 + W_ * C_);
        bf16x8 v11 = *reinterpret_cast<const bf16x8*>(p00 + W_ * C_ + C_);
        float w0 = sw[j][0], w1 = sw[j][1], w2 = sw[j][2], w3 = sw[j][3];
        #pragma unroll
        for (int e = 0; e < 8; ++e) {
            sX[j][c8 + e] = bf2f((unsigned short)v00[e]) * w0 +
                            bf2f((unsigned short)v01[e]) * w1 +
                            bf2f((unsigned short)v10[e]) * w2 +
                            bf2f((unsigned short)v11[e]) * w3;
        }
    }
    __syncthreads();
    size_t obase = (size_t)n * J_ * C_;
    for (int c = threadIdx.x; c < C_; c += 256) {
        float xv[J_];
        #pragma unroll
        for (int k = 0; k < J_; k++) xv[k] = sX[k][c];
        #pragma unroll
        for (int j = 0; j < J_; j++) {
            float s = 0.f;
            #pragma unroll
            for (int k = 0; k < J_; k++) s += sadj[j * J_ + k] * xv[k];
            Ah[obase + (size_t)j * C_ + c] = (short)f2bf(s);
        }
    }
}

// ---------------- weight -> single bf16, padded [NPAD][K] ----------------
__global__ __launch_bounds__(256) void k_wsplit(const float* __restrict__ Wh,
                                                const float* __restrict__ Wres,
                                                const float* __restrict__ Wp1,
                                                short* __restrict__ WtH,
                                                short* __restrict__ WpH) {
    int gid = blockIdx.x * 256 + threadIdx.x;
    const int t1 = NMAT * NPAD * C_;
    const int t2 = NPAD * 3 * C_;
    if (gid < t1) {
        int m   = gid / (NPAD * C_);
        int rem = gid % (NPAD * C_);
        int n = rem / C_;
        int k = rem % C_;
        float v = 0.f;
        if (n < C_) {
            const float* src = (m == 0) ? Wh : (Wres + (size_t)(m - 1) * C_ * C_);
            v = src[(size_t)k * C_ + n];
        }
        WtH[gid] = (short)f2bf(v);
    } else if (gid < t1 + t2) {
        int g2 = gid - t1;
        int n = g2 / (3 * C_);
        int k = g2 % (3 * C_);
        float v = (n < C_) ? Wp1[(size_t)n * 3 * C_ + k] : 0.f;
        WpH[g2] = (short)f2bf(v);
    }
}

// ---------------- adjacency mix on bf16: A[n,j,:] = sum_k adj[j,k] X[n,k,:] ----------------
__global__ __launch_bounds__(256) void k_mix_bf16(const short* __restrict__ Xin,
                                                  const float* __restrict__ adj,
                                                  short* __restrict__ Ah) {
    __shared__ float sadj[J_ * J_];
    for (int t = threadIdx.x; t < J_ * J_; t += 256) sadj[t] = adj[t];
    __syncthreads();
    int t = threadIdx.x;
    if (t >= 240) return;
    int n  = blockIdx.x * 2 + (t / 120);
    int c4 = (t % 120) * 4;
    const short* xb = Xin + (size_t)n * J_ * C_ + c4;
    float xf[J_][4];
    #pragma unroll
    for (int k = 0; k < J_; k++) {
        bf16x4 v = *reinterpret_cast<const bf16x4*>(xb + (size_t)k * C_);
        #pragma unroll
        for (int e = 0; e < 4; ++e) xf[k][e] = bf2f((unsigned short)v[e]);
    }
    short* yb = Ah + (size_t)n * J_ * C_ + c4;
    #pragma unroll
    for (int j = 0; j < J_; j++) {
        float a0 = 0.f, a1 = 0.f, a2 = 0.f, a3 = 0.f;
        #pragma unroll
        for (int k = 0; k < J_; k++) {
            float w = sadj[j * J_ + k];
            a0 = fmaf(w, xf[k][0], a0);
            a1 = fmaf(w, xf[k][1], a1);
            a2 = fmaf(w, xf[k][2], a2);
            a3 = fmaf(w, xf[k][3], a3);
        }
        bf16x4 o = {(short)f2bf(a0), (short)f2bf(a1), (short)f2bf(a2), (short)f2bf(a3)};
        *reinterpret_cast<bf16x4*>(yb + (size_t)j * C_) = o;
    }
}

// ---------------- 1-term bf16 MFMA GEMM: 3-buffer counted-vmcnt pipeline (T4) ----------------
// out[m,n](bf16) = relu(bn(sum_k A[m,k]B[k,n] + bias[n])) (+ res bf16)
// Per iter ks: issue gload_lds for ks+2 -> buf[(ks+2)%3]; s_waitcnt vmcnt(8) (only step-ks's
// 4 loads drain; ks+1/ks+2 stay in flight); s_barrier; ds_read+MFMA; s_barrier.
// Buffer-reuse audit: buf[(ks+2)%3] was last READ at step ks-1; all waves' reads completed
// before barrier-2 of iter ks-1, which precedes this iter's issue in program order.
template <bool ADD>
__global__ __launch_bounds__(256) void k_gemm_mfma(const short* __restrict__ A,
                                                   const short* __restrict__ Bm,
                                                   const float* __restrict__ bias,
                                                   const float* __restrict__ bn4,
                                                   const short* res,   // may alias out
                                                   short* out,
                                                   int M, int N, int K) {
    __shared__ short lds[3 * 2 * 4096];   // 3 bufs x [sA|sB], 48 KB

    // bijective XCD-chunked swizzle (nwg % 8 == 0 guaranteed by caller)
    int nwg = gridDim.x * gridDim.y;
    int lin = blockIdx.y * gridDim.x + blockIdx.x;
    int cpx = nwg >> 3;
    int swz = (lin & 7) * cpx + (lin >> 3);
    const int row0 = (swz / gridDim.x) * 128;
    const int col0 = (swz % gridDim.x) * 128;

    const int tid  = threadIdx.x;
    const int lane = tid & 63;
    const int wid  = tid >> 6;
    const int wm0  = (wid >> 1) * 64;
    const int wn0  = (wid & 1) * 64;

    f32x4 acc[4][4];
    #pragma unroll
    for (int i = 0; i < 4; i++)
        #pragma unroll
        for (int j = 0; j < 4; j++) acc[i][j] = (f32x4){0.f, 0.f, 0.f, 0.f};

    const int kq = lane >> 4;
    const int fr = lane & 15;

    // per-lane inverse-swizzle source mapping for this wave's two 1KB staging slices
    int r_[2], cq_[2];
    #pragma unroll
    for (int t = 0; t < 2; ++t) {
        int p = (2 * wid + t) * 1024 + lane * 16;
        int v = p >> 6;
        int r = v ^ ((v >> 2) & 1);
        r_[t]  = r;
        cq_[t] = ((p >> 4) & 3) ^ (r & 3);
    }
    const short* pA0 = A  + (size_t)(row0 + r_[0]) * K + cq_[0] * 8;
    const short* pA1 = A  + (size_t)(row0 + r_[1]) * K + cq_[1] * 8;
    const short* pB0 = Bm + (size_t)(col0 + r_[0]) * K + cq_[0] * 8;
    const short* pB1 = Bm + (size_t)(col0 + r_[1]) * K + cq_[1] * 8;
    const int a0 = (2 * wid + 0) * 1024;    // byte offsets inside one buffer
    const int a1 = (2 * wid + 1) * 1024;

    const int NS = K / 32;
    // prologue: stage step 0 -> buf0, step 1 -> buf1 (4 gload_lds per wave per step)
    {
        char* lb = (char*)lds;
        GLD16(pA0, lb + a0);             GLD16(pA1, lb + a1);
        GLD16(pB0, lb + 8192 + a0);      GLD16(pB1, lb + 8192 + a1);
        char* lb1 = (char*)lds + 16384;
        GLD16(pA0 + 32, lb1 + a0);       GLD16(pA1 + 32, lb1 + a1);
        GLD16(pB0 + 32, lb1 + 8192 + a0);GLD16(pB1 + 32, lb1 + 8192 + a1);
    }

    for (int ks = 0; ks < NS; ++ks) {
        // ---- issue step ks+2 into buf[(ks+2)%3], then wait ONLY step ks's loads ----
        if (ks + 2 < NS) {
            const int kk = (ks + 2) * 32;
            char* lb = (char*)lds + ((ks + 2) % 3) * 16384;
            GLD16(pA0 + kk, lb + a0);        GLD16(pA1 + kk, lb + a1);
            GLD16(pB0 + kk, lb + 8192 + a0); GLD16(pB1 + kk, lb + 8192 + a1);
            asm volatile("s_waitcnt vmcnt(8)" ::: "memory");
        } else if (ks + 1 < NS) {
            asm volatile("s_waitcnt vmcnt(4)" ::: "memory");
        } else {
            asm volatile("s_waitcnt vmcnt(0)" ::: "memory");
        }
        __builtin_amdgcn_sched_barrier(0);
        asm volatile("s_barrier" ::: "memory");   // all waves' step-ks loads landed

        const short* lbc = lds + (ks % 3) * 8192;
        bf16x8 fa[4], fb[4];
        #pragma unroll
        for (int mf = 0; mf < 4; ++mf) {
            int r  = wm0 + mf * 16 + fr;
            int so = ((r * 64 + kq * 16) ^ ((r & 7) << 4)) >> 1;
            fa[mf] = *reinterpret_cast<const bf16x8*>(lbc + so);
        }
        #pragma unroll
        for (int nf = 0; nf < 4; ++nf) {
            int r  = wn0 + nf * 16 + fr;
            int so = ((r * 64 + kq * 16) ^ ((r & 7) << 4)) >> 1;
            fb[nf] = *reinterpret_cast<const bf16x8*>(lbc + 4096 + so);
        }
        __builtin_amdgcn_s_setprio(1);
        #pragma unroll
        for (int mf = 0; mf < 4; ++mf)
            #pragma unroll
            for (int nf = 0; nf < 4; ++nf)
                acc[mf][nf] = __builtin_amdgcn_mfma_f32_16x16x32_bf16(fa[mf], fb[nf], acc[mf][nf], 0, 0, 0);
        __builtin_amdgcn_s_setprio(0);
        asm volatile("s_barrier" ::: "memory");   // reads done -> buffer may be reused
    }

    // ---- epilogue: C/D layout col=lane&15, row=(lane>>4)*4+reg ----
    const int rq = lane >> 4;
    #pragma unroll
    for (int nf = 0; nf < 4; ++nf) {
        int col = col0 + wn0 + nf * 16 + fr;
        if (col >= N) continue;
        float bia = bias[col];
        float g   = bn4[col];
        float be  = bn4[N + col];
        float mu  = bn4[2 * N + col];
        float va  = bn4[3 * N + col];
        float sc  = rsqrtf(va + EPS_) * g;
        #pragma unroll
        for (int mf = 0; mf < 4; ++mf) {
            #pragma unroll
            for (int r = 0; r < 4; ++r) {
                int row = row0 + wm0 + mf * 16 + rq * 4 + r;
                float v = acc[mf][nf][r] + bia;
                v = (v - mu) * sc + be;
                v = fmaxf(v, 0.f);
                if (ADD) v += bf2f((unsigned short)res[(size_t)row * N + col]);
                out[(size_t)row * N + col] = (short)f2bf(v);
            }
        }
    }
}

// ---------------- pooling + concat (+center direct from NHWC) -> bf16 feats [NSAMP][3C] ----------------
__global__ __launch_bounds__(256) void k_pool(const short* __restrict__ Hb,
                                              const short* __restrict__ nhwc,
                                              const int* __restrict__ cidx,
                                              short* __restrict__ feats) {
    int n = blockIdx.x;
    int b = n / NP_;
    const short* cen = nhwc + ((size_t)b * HW_ + cidx[n]) * C_;
    for (int c = threadIdx.x; c < C_; c += 256) {
        float s = 0.f, m = -INFINITY;
        #pragma unroll
        for (int j = 0; j < J_; j++) {
            float v = bf2f((unsigned short)Hb[((size_t)n * J_ + j) * C_ + c]);
            s += v;
            m = fmaxf(m, v);
        }
        feats[(size_t)n * 3 * C_ + c]          = (short)f2bf(s * (1.f / (float)J_));
        feats[(size_t)n * 3 * C_ + C_ + c]     = (short)f2bf(m);
        feats[(size_t)n * 3 * C_ + 2 * C_ + c] = cen[c];
    }
}

// ---------------- final projection (P bf16) ----------------
__global__ __launch_bounds__(256) void k_final(const short* __restrict__ P,
                                               const float* __restrict__ W2,
                                               const float* __restrict__ b2,
                                               float* __restrict__ out) {
    int g = blockIdx.x * 256 + threadIdx.x;
    if (g >= NSAMP * 2 * J_) return;
    int m = g / (2 * J_);
    int o = g % (2 * J_);
    const short* pr = P + (size_t)m * C_;
    const float* wr = W2 + (size_t)o * C_;
    float s = 0.f;
    for (int k = 0; k < C_; k += 4) {
        s = fmaf(bf2f((unsigned short)pr[k + 0]), wr[k + 0], s);
        s = fmaf(bf2f((unsigned short)pr[k + 1]), wr[k + 1], s);
        s = fmaf(bf2f((unsigned short)pr[k + 2]), wr[k + 2], s);
        s = fmaf(bf2f((unsigned short)pr[k + 3]), wr[k + 3], s);
    }
    out[g] = s + b2[o];
}

extern "C" void kernel_launch(void* const* d_in, const int* in_sizes, int n_in,
                              void* d_out, int out_size, void* d_ws, size_t ws_size,
                              hipStream_t stream) {
    const float* features = (const float*)d_in[0];
    const float* coords   = (const float*)d_in[1];
    const int*   center   = (const int*)d_in[2];
    const float* adj      = (const float*)d_in[3];
    const float* Wh       = (const float*)d_in[4];
    const float* bh       = (const float*)d_in[5];
    const float* bn_head  = (const float*)d_in[6];
    const float* Wres     = (const float*)d_in[7];
    const float* bres     = (const float*)d_in[8];
    const float* bn_res   = (const float*)d_in[9];
    const float* Wp1      = (const float*)d_in[10];
    const float* bp1      = (const float*)d_in[11];
    const float* bn_pred  = (const float*)d_in[12];
    const float* Wp2      = (const float*)d_in[13];
    const float* bp2      = (const float*)d_in[14];
    float* out = (float*)d_out;

    // ---- workspace layout ----
    char* ws = (char*)d_ws;
    short* nhwc  = (short*)ws;   ws += (size_t)B_ * HW_ * C_ * 2;     // bf16 NHWC
    short* bufX  = (short*)ws;   ws += (size_t)MROWS * C_ * 2;        // bf16 [MROWS,C]
    short* bufH  = (short*)ws;   ws += (size_t)MROWS * C_ * 2;
    short* AhB   = (short*)ws;   ws += (size_t)MROWS * C_ * 2;        // bf16 A
    short* featsB= (short*)ws;   ws += (size_t)NSAMP * 3 * C_ * 2;    // bf16 feats
    short* bufP  = (short*)ws;   ws += (size_t)NSAMP * C_ * 2;        // bf16 pred
    short* WtH   = (short*)ws;   ws += (size_t)NMAT * NPAD * C_ * 2;  // padded [512][480]
    short* WpH   = (short*)ws;   ws += (size_t)NPAD * 3 * C_ * 2;     // padded [512][1440]

    dim3 gg(4, MROWS / 128);          // 544 blocks (544 % 8 == 0)
    dim3 gp(4, NSAMP / 128);          // 32 blocks  (32 % 8 == 0)
    dim3 gt(HW_ / TS, C_ / TC, B_);   // transpose tiles

    int wtot = NMAT * NPAD * C_ + NPAD * 3 * C_;
    k_wsplit<<<(wtot + 255) / 256, 256, 0, stream>>>(Wh, Wres, Wp1, WtH, WpH);
    k_nhwc<<<gt, 256, 0, stream>>>(features, nhwc);

    // head block
    k_gather_mix<<<NSAMP, 256, 0, stream>>>(nhwc, coords, adj, AhB);
    k_gemm_mfma<false><<<gg, 256, 0, stream>>>(AhB, WtH, bh, bn_head,
                                               nullptr, bufH, MROWS, C_, C_);

    for (int i = 0; i < L_; i++) {
        int m1 = 1 + 2 * i, m2 = 2 + 2 * i;
        k_mix_bf16<<<NSAMP / 2, 256, 0, stream>>>(bufH, adj, AhB);
        k_gemm_mfma<false><<<gg, 256, 0, stream>>>(
            AhB, WtH + (size_t)m1 * NPAD * C_,
            bres + (size_t)(2 * i) * C_, bn_res + (size_t)(2 * i) * 4 * C_,
            nullptr, bufX, MROWS, C_, C_);
        k_mix_bf16<<<NSAMP / 2, 256, 0, stream>>>(bufX, adj, AhB);
        k_gemm_mfma<true><<<gg, 256, 0, stream>>>(
            AhB, WtH + (size_t)m2 * NPAD * C_,
            bres + (size_t)(2 * i + 1) * C_, bn_res + (size_t)(2 * i + 1) * 4 * C_,
            bufH, bufH, MROWS, C_, C_);
    }

    k_pool<<<NSAMP, 256, 0, stream>>>(bufH, nhwc, center, featsB);

    // pred: relu(bn(feats @ Wp1^T + bp1)); M=1024, N=480, K=1440
    k_gemm_mfma<false><<<gp, 256, 0, stream>>>(featsB, WpH, bp1, bn_pred,
                                               nullptr, bufP, NSAMP, C_, 3 * C_);

    k_final<<<(NSAMP * 2 * J_ + 255) / 256, 256, 0, stream>>>(bufP, Wp2, bp2, out);
}